// Round 1
// baseline (1323.206 us; speedup 1.0000x reference)
//
#include <hip/hip_runtime.h>
#include <hip/hip_bf16.h>
#include <math.h>

#define BB 2
#define HH 32
#define WW 32
#define LL 1024
#define DM 192
#define DI 384
#define NS 16
#define RR 12
#define KK 4
#define CC 44   /* RR + 2*NS */

// ---- dtype-flex loads (flag: 0=fp32, 1=bf16), decided on-device from Ds[0] ----
__device__ __forceinline__ float ldin(const void* p, int i, int bf) {
  if (bf) return __bfloat162float(((const __hip_bfloat16*)p)[i]);
  return ((const float*)p)[i];
}
__device__ __forceinline__ float sigm(float x){ return 1.f/(1.f + __expf(-x)); }
__device__ __forceinline__ float softplusf(float x){ return (x > 20.f) ? x : log1pf(__expf(x)); }

// scan-index -> physical (row-major h*W+w) index for direction k
__device__ __forceinline__ int permk(int k, int l){
  if (k == 0) return l;
  if (k == 2) return LL-1-l;
  int lr = (k == 3) ? (LL-1-l) : l;
  return (lr & 31)*WW + (lr >> 5);   // (l%H)*W + (l/H)
}

__global__ void k_detect(const unsigned* ds, int* flag){
  *flag = (*ds == 0x3F800000u) ? 0 : 1;   // fp32 ones vs bf16 pair 0x3F803F80
}

// xz = x @ in_proj_w.T (split into xp, z), xc = x_cross @ in_proj_cross_w.T
// 8 positions per block staged in LDS for weight reuse.
__global__ __launch_bounds__(256) void k_inproj(const void* x, const void* xcr,
    const void* wi, const void* wc, const int* flagp,
    float* xp, float* z, float* xc){
  const int bf = *flagp;
  __shared__ float xs_[8][DM];
  __shared__ float xcs_[8][DM];
  const int t = threadIdx.x;
  const int pos0 = blockIdx.x * 8;
  for (int i = t; i < 8*DM; i += 256) {
    int p = i / DM, j = i % DM;
    xs_[p][j]  = ldin(x,   (pos0+p)*DM + j, bf);
    xcs_[p][j] = ldin(xcr, (pos0+p)*DM + j, bf);
  }
  __syncthreads();
  typedef float row192[DM];
  for (int o = t; o < 1152; o += 256) {
    const row192* tile = (o < 768) ? (const row192*)xs_ : (const row192*)xcs_;
    const void* wb = (o < 768) ? wi : wc;
    const int row = (o < 768) ? o : (o - 768);
    float acc[8];
    #pragma unroll
    for (int p=0;p<8;p++) acc[p]=0.f;
    for (int j=0;j<DM;j++) {
      float wv = ldin(wb, row*DM + j, bf);
      #pragma unroll
      for (int p=0;p<8;p++) acc[p] = fmaf(wv, tile[p][j], acc[p]);
    }
    #pragma unroll
    for (int p=0;p<8;p++) {
      int pos = pos0 + p;
      if (o < 384)      xp[pos*DI + o]        = acc[p];
      else if (o < 768) z [pos*DI + (o-384)]  = acc[p];
      else              xc[pos*DI + (o-768)]  = acc[p];
    }
  }
}

// depthwise 3x3 conv + bias + SiLU; layout [b, l(=h*W+w), d]
__global__ __launch_bounds__(256) void k_conv(const float* xp, const void* cw, const void* cb,
    const int* flagp, float* xh){
  const int bf = *flagp;
  const int idx = blockIdx.x*256 + threadIdx.x;    // B*L*DI = 786432 exact
  const int d = idx % DI;
  const int l = (idx / DI) % LL;
  const int b = idx / (DI*LL);
  const int h = l >> 5, w = l & 31;
  float acc = ldin(cb, d, bf);
  #pragma unroll
  for (int kh=0; kh<3; kh++){
    const int hh = h + kh - 1;
    if (hh < 0 || hh >= HH) continue;
    #pragma unroll
    for (int kw=0; kw<3; kw++){
      const int ww2 = w + kw - 1;
      if (ww2 < 0 || ww2 >= WW) continue;
      acc = fmaf(xp[(b*LL + hh*WW + ww2)*DI + d], ldin(cw, d*9 + kh*3 + kw, bf), acc);
    }
  }
  xh[idx] = acc * sigm(acc);
}

// per (b,k,l): x_dbl = x_proj_weight[k] @ xsc_row (44 ch) -> dts/B/C; dt_proj + softplus -> delta
__global__ __launch_bounds__(64) void k_xproj(const float* xc, const void* xpw,
    const void* dtw, const void* dtb, const int* flagp,
    float* delta, float* Bm, float* Cm){
  const int bf = *flagp;
  const int blk = blockIdx.x;          // B*K*L = 8192
  const int b = blk >> 12;
  const int k = (blk >> 10) & 3;
  const int l = blk & 1023;
  const int t = threadIdx.x;
  __shared__ float xrow[DI];
  __shared__ float dts[RR];
  const int pl = permk(k, l);
  for (int i=t; i<DI; i+=64) xrow[i] = xc[(b*LL + pl)*DI + i];
  __syncthreads();
  if (t < CC) {
    float acc = 0.f;
    const int wbase = k*CC*DI + t*DI;
    for (int d=0; d<DI; d++) acc = fmaf(ldin(xpw, wbase+d, bf), xrow[d], acc);
    if (t < RR)            dts[t] = acc;
    else if (t < RR+NS)    Bm[((b*KK+k)*LL + l)*NS + (t-RR)]    = acc;
    else                   Cm[((b*KK+k)*LL + l)*NS + (t-RR-NS)] = acc;
  }
  __syncthreads();
  #pragma unroll
  for (int j=0;j<6;j++){
    const int d = j*64 + t;
    float acc = ldin(dtb, k*DI + d, bf);
    #pragma unroll
    for (int r=0;r<RR;r++) acc = fmaf(ldin(dtw, (k*DI+d)*RR + r, bf), dts[r], acc);
    delta[((b*KK+k)*LL + l)*DI + d] = softplusf(acc);
  }
}

// selective scan; 16 lanes per (b,k,d) chain (one state n each); scanY aliases delta buffer
__global__ __launch_bounds__(256) void k_scan(float* delta, const float* xh,
    const float* Bm, const float* Cm, const void* alogs, const int* flagp){
  const int bf = *flagp;
  const int blk = blockIdx.x;          // B*K*(DI/16) = 192
  const int b = blk / 96;
  const int rem = blk % 96;
  const int k = rem / 24;
  const int dblk = rem % 24;
  const int t = threadIdx.x;
  const int d = dblk*16 + (t >> 4);
  const int n = t & 15;
  const float An = -__expf(ldin(alogs, (k*DI + d)*NS + n, bf));
  float h = 0.f;
  const int dbase  = ((b*KK+k)*LL)*DI + d;
  const int bcbase = ((b*KK+k)*LL)*NS + n;
  const int xbase  = b*LL*DI + d;
  for (int l=0; l<LL; l++){
    const int pl = permk(k, l);
    const float dl = delta[dbase + l*DI];
    const float u  = xh[xbase + pl*DI];
    const float Bn = Bm[bcbase + l*NS];
    const float Cn = Cm[bcbase + l*NS];
    const float dA = __expf(dl * An);
    h = fmaf(dA, h, dl*u*Bn);
    float p = h * Cn;
    p += __shfl_xor(p, 1, 16);
    p += __shfl_xor(p, 2, 16);
    p += __shfl_xor(p, 4, 16);
    p += __shfl_xor(p, 8, 16);
    if (n == 0) delta[dbase + l*DI] = p;   // write y_sum; all 16 lanes read before this store (lockstep)
  }
}

// merge 4 directions (+D*u folded to xh * sum_k Ds) + LayerNorm + SiLU(z) gate + out-proj
__global__ __launch_bounds__(256) void k_merge(const float* scanY, const float* xh,
    const float* z, const void* dsP, const void* gP, const void* bP, const void* woP,
    const int* flagp, void* out){
  const int bf = *flagp;
  const int blk = blockIdx.x;          // B*L = 2048
  const int b = blk >> 10;
  const int l = blk & 1023;
  const int h = l >> 5, w = l & 31;
  const int lt = w*32 + h;
  const int t = threadIdx.x;
  __shared__ float yb[DI];
  __shared__ float stats[2];
  __shared__ float wred[4], wred2[4];
  float s = 0.f, s2 = 0.f;
  for (int d=t; d<DI; d+=256){
    float y = scanY[((b*KK+0)*LL + l        )*DI + d]
            + scanY[((b*KK+2)*LL + (LL-1-l ))*DI + d]
            + scanY[((b*KK+1)*LL + lt       )*DI + d]
            + scanY[((b*KK+3)*LL + (LL-1-lt))*DI + d];
    const float dsum = ldin(dsP, d, bf) + ldin(dsP, DI+d, bf)
                     + ldin(dsP, 2*DI+d, bf) + ldin(dsP, 3*DI+d, bf);
    y = fmaf(xh[(b*LL+l)*DI + d], dsum, y);
    yb[d] = y;
    s += y; s2 = fmaf(y, y, s2);
  }
  #pragma unroll
  for (int m=32;m>=1;m>>=1){ s += __shfl_down(s, m); s2 += __shfl_down(s2, m); }
  if ((t & 63) == 0){ wred[t>>6] = s; wred2[t>>6] = s2; }
  __syncthreads();
  if (t == 0){
    float a=0.f, c=0.f;
    #pragma unroll
    for (int i=0;i<4;i++){ a += wred[i]; c += wred2[i]; }
    const float mu = a / DI;
    const float var = fmaxf(c / DI - mu*mu, 0.f);
    stats[0] = mu;
    stats[1] = rsqrtf(var + 1e-5f);
  }
  __syncthreads();
  const float mu = stats[0], rs = stats[1];
  for (int d=t; d<DI; d+=256){
    float yn = (yb[d]-mu)*rs*ldin(gP, d, bf) + ldin(bP, d, bf);
    const float zg = z[(b*LL+l)*DI + d];
    yb[d] = yn * zg * sigm(zg);
  }
  __syncthreads();
  if (t < DM){
    float acc = 0.f;
    for (int d=0; d<DI; d++) acc = fmaf(ldin(woP, t*DI + d, bf), yb[d], acc);
    if (bf) ((__hip_bfloat16*)out)[(b*LL+l)*DM + t] = __float2bfloat16(acc);
    else    ((float*)out)[(b*LL+l)*DM + t] = acc;
  }
}

extern "C" void kernel_launch(void* const* d_in, const int* in_sizes, int n_in,
                              void* d_out, int out_size, void* d_ws, size_t ws_size,
                              hipStream_t stream){
  const void* x    = d_in[0];
  const void* xcr  = d_in[1];
  const void* wi   = d_in[2];
  const void* wc   = d_in[3];
  const void* cw   = d_in[4];
  const void* cb   = d_in[5];
  const void* xpw  = d_in[6];
  const void* dtw  = d_in[7];
  const void* dtb  = d_in[8];
  const void* alog = d_in[9];
  const void* dsv  = d_in[10];
  const void* gno  = d_in[11];
  const void* bno  = d_in[12];
  const void* wo   = d_in[13];

  float* ws = (float*)d_ws;
  int*   flag = (int*)ws;
  float* xp    = ws + 16;
  float* z     = xp    + (size_t)BB*LL*DI;
  float* xc    = z     + (size_t)BB*LL*DI;
  float* xh    = xc    + (size_t)BB*LL*DI;
  float* delta = xh    + (size_t)BB*LL*DI;           // scanY aliases this after k_scan
  float* Bm    = delta + (size_t)BB*KK*LL*DI;
  float* Cm    = Bm    + (size_t)BB*KK*LL*NS;
  // total: 16 + 4*786432 + 3145728 + 2*131072 floats = ~26.2 MB

  k_detect<<<1, 1, 0, stream>>>((const unsigned*)dsv, flag);
  k_inproj<<<BB*LL/8, 256, 0, stream>>>(x, xcr, wi, wc, flag, xp, z, xc);
  k_conv  <<<BB*LL*DI/256, 256, 0, stream>>>(xp, cw, cb, flag, xh);
  k_xproj <<<BB*KK*LL, 64, 0, stream>>>(xc, xpw, dtw, dtb, flag, delta, Bm, Cm);
  k_scan  <<<BB*KK*(DI/16), 256, 0, stream>>>(delta, xh, Bm, Cm, alog, flag);
  k_merge <<<BB*LL, 256, 0, stream>>>(delta, xh, z, dsv, gno, bno, wo, flag, d_out);
}

// Round 2
// 407.234 us; speedup vs baseline: 3.2492x; 3.2492x over previous
//
#include <hip/hip_runtime.h>
#include <hip/hip_bf16.h>
#include <math.h>

#define BB 2
#define HH 32
#define WW 32
#define LL 1024
#define DM 192
#define DI 384
#define NS 16
#define RR 12
#define KK 4
#define CC 44   /* RR + 2*NS */
#define NC 16   /* scan chunks */
#define LC 64   /* chunk length */
#define GG 196608  /* B*K*DI*NS */

// ---- dtype-flex loads (flag: 0=fp32, 1=bf16), decided on-device from Ds[0] ----
__device__ __forceinline__ float ldin(const void* p, int i, int bf) {
  if (bf) {
    unsigned v = ((const unsigned short*)p)[i];
    return __uint_as_float(v << 16);
  }
  return ((const float*)p)[i];
}
// 4-wide flex load; i must be a multiple of 4
__device__ __forceinline__ float4 ldin4(const void* p, int i, int bf) {
  if (bf) {
    ushort4 u = ((const ushort4*)p)[i >> 2];
    float4 r;
    r.x = __uint_as_float((unsigned)u.x << 16);
    r.y = __uint_as_float((unsigned)u.y << 16);
    r.z = __uint_as_float((unsigned)u.z << 16);
    r.w = __uint_as_float((unsigned)u.w << 16);
    return r;
  }
  return ((const float4*)p)[i >> 2];
}
__device__ __forceinline__ float sigm(float x){ return 1.f/(1.f + __expf(-x)); }
__device__ __forceinline__ float softplusf(float x){ return (x > 20.f) ? x : log1pf(__expf(x)); }

// scan-index -> physical (row-major h*W+w) index for direction k
__device__ __forceinline__ int permk(int k, int l){
  if (k == 0) return l;
  if (k == 2) return LL-1-l;
  int lr = (k == 3) ? (LL-1-l) : l;
  return (lr & 31)*WW + (lr >> 5);   // (l%H)*W + (l/H)
}

__global__ void k_detect(const unsigned* ds, int* flag){
  *flag = (*ds == 0x3F800000u) ? 0 : 1;   // fp32 ones vs bf16 pair 0x3F803F80
}

// xz = x @ in_proj_w.T (split into xp, z), xc = x_cross @ in_proj_cross_w.T
// 8 positions per block staged in LDS; 3 row-groups (xp / z / xc) -> 768 blocks.
__global__ __launch_bounds__(256) void k_inproj(const void* x, const void* xcr,
    const void* wi, const void* wc, const int* flagp,
    float* xp, float* z, float* xc){
  const int bf = *flagp;
  __shared__ float xs_[8][DM];
  const int t = threadIdx.x;
  const int rg = blockIdx.x >> 8;            // 0: xp rows, 1: z rows, 2: xc rows
  const int pos0 = (blockIdx.x & 255) * 8;
  const void* src = (rg == 2) ? xcr : x;
  for (int i = t*4; i < 8*DM; i += 1024) {
    float4 v = ldin4(src, pos0*DM + i, bf);
    *(float4*)&(((float*)xs_)[i]) = v;
  }
  __syncthreads();
  const void* wb = (rg == 2) ? wc : wi;
  const int rbase = (rg == 1) ? 384 : 0;
  float* dst = (rg == 0) ? xp : (rg == 1 ? z : xc);
  for (int o = t; o < 384; o += 256) {
    const int row = rbase + o;
    float acc[8];
    #pragma unroll
    for (int p=0;p<8;p++) acc[p]=0.f;
    for (int j=0;j<DM;j+=4) {
      float4 wv = ldin4(wb, row*DM + j, bf);
      #pragma unroll
      for (int p=0;p<8;p++){
        float4 xv = *(const float4*)&xs_[p][j];
        acc[p] = fmaf(wv.x, xv.x, acc[p]);
        acc[p] = fmaf(wv.y, xv.y, acc[p]);
        acc[p] = fmaf(wv.z, xv.z, acc[p]);
        acc[p] = fmaf(wv.w, xv.w, acc[p]);
      }
    }
    #pragma unroll
    for (int p=0;p<8;p++) dst[(pos0+p)*DI + o] = acc[p];
  }
}

// depthwise 3x3 conv + bias + SiLU; layout [b, l(=h*W+w), d]
__global__ __launch_bounds__(256) void k_conv(const float* __restrict__ xp,
    const void* cw, const void* cb, const int* flagp, float* __restrict__ xh){
  const int bf = *flagp;
  const int idx = blockIdx.x*256 + threadIdx.x;    // B*L*DI = 786432 exact
  const int d = idx % DI;
  const int l = (idx / DI) % LL;
  const int b = idx / (DI*LL);
  const int h = l >> 5, w = l & 31;
  float acc = ldin(cb, d, bf);
  #pragma unroll
  for (int kh=0; kh<3; kh++){
    const int hh = h + kh - 1;
    if (hh < 0 || hh >= HH) continue;
    #pragma unroll
    for (int kw=0; kw<3; kw++){
      const int ww2 = w + kw - 1;
      if (ww2 < 0 || ww2 >= WW) continue;
      acc = fmaf(xp[(b*LL + hh*WW + ww2)*DI + d], ldin(cw, d*9 + kh*3 + kw, bf), acc);
    }
  }
  xh[idx] = acc * sigm(acc);
}

// per (b,k,l): x_dbl = x_proj_weight[k] @ xsc_row (44 ch) -> dts/B/C; dt_proj + softplus -> delta
__global__ __launch_bounds__(64) void k_xproj(const float* __restrict__ xc, const void* xpw,
    const void* dtw, const void* dtb, const int* flagp,
    float* delta, float* Bm, float* Cm){
  const int bf = *flagp;
  const int blk = blockIdx.x;          // B*K*L = 8192
  const int b = blk >> 12;
  const int k = (blk >> 10) & 3;
  const int l = blk & 1023;
  const int t = threadIdx.x;
  __shared__ float xrow[DI];
  __shared__ float dts[RR];
  const int pl = permk(k, l);
  for (int i=t*4; i<DI; i+=256) *(float4*)&xrow[i] = *(const float4*)&xc[(b*LL + pl)*DI + i];
  __syncthreads();
  if (t < CC) {
    float acc = 0.f;
    const int wbase = k*CC*DI + t*DI;
    for (int d=0; d<DI; d+=4){
      float4 wv = ldin4(xpw, wbase+d, bf);
      float4 xv = *(const float4*)&xrow[d];
      acc = fmaf(wv.x, xv.x, acc);
      acc = fmaf(wv.y, xv.y, acc);
      acc = fmaf(wv.z, xv.z, acc);
      acc = fmaf(wv.w, xv.w, acc);
    }
    if (t < RR)            dts[t] = acc;
    else if (t < RR+NS)    Bm[((b*KK+k)*LL + l)*NS + (t-RR)]    = acc;
    else                   Cm[((b*KK+k)*LL + l)*NS + (t-RR-NS)] = acc;
  }
  __syncthreads();
  #pragma unroll
  for (int j=0;j<6;j++){
    const int d = j*64 + t;
    float acc = ldin(dtb, k*DI + d, bf);
    const int wb2 = (k*DI+d)*RR;
    #pragma unroll
    for (int r=0;r<RR;r+=4){
      float4 wv = ldin4(dtw, wb2+r, bf);
      acc = fmaf(wv.x, dts[r],   acc);
      acc = fmaf(wv.y, dts[r+1], acc);
      acc = fmaf(wv.z, dts[r+2], acc);
      acc = fmaf(wv.w, dts[r+3], acc);
    }
    delta[((b*KK+k)*LL + l)*DI + d] = softplusf(acc);
  }
}

// ---- chunked selective scan, 3 passes ----
// Pass A: per-chunk local scan from h=0; emit cumulative dA product + local end state.
__global__ __launch_bounds__(256) void k_scanA(const float* __restrict__ delta,
    const float* __restrict__ xh, const float* __restrict__ Bm,
    const void* alogs, const int* flagp,
    float* __restrict__ Acum, float* __restrict__ Hend){
  const int bf = *flagp;
  const int blk = blockIdx.x;          // B*K*24*NC = 3072
  const int c = blk & (NC-1);
  const int r = blk >> 4;
  const int dblk = r % 24;
  const int k = (r / 24) & 3;
  const int b = r / 96;
  const int t = threadIdx.x;
  const int d = dblk*16 + (t >> 4);
  const int n = t & 15;
  const float An = -__expf(ldin(alogs, (k*DI + d)*NS + n, bf));
  const int dbase  = ((b*KK+k)*LL)*DI + d;
  const int bcbase = ((b*KK+k)*LL)*NS + n;
  const int xbase  = b*LL*DI + d;
  float h = 0.f, Ac = 1.f;
  const int l0 = c*LC;
  #pragma unroll 4
  for (int l = l0; l < l0+LC; l++){
    const float dl = delta[dbase + l*DI];
    const float u  = xh[xbase + permk(k,l)*DI];
    const float Bn = Bm[bcbase + l*NS];
    const float dA = __expf(dl * An);
    Ac *= dA;
    h = fmaf(dA, h, dl*u*Bn);
  }
  const int gid = ((b*KK + k)*DI + d)*NS + n;
  Acum[c*GG + gid] = Ac;
  Hend[c*GG + gid] = h;
}

// Pass B: serial scan over the NC chunk summaries; Hend becomes Hin in-place.
__global__ __launch_bounds__(256) void k_scanB(const float* __restrict__ Acum,
    float* __restrict__ Hend){
  const int gid = blockIdx.x*256 + threadIdx.x;   // GG threads
  float h = 0.f;
  #pragma unroll
  for (int c = 0; c < NC; c++){
    const float a = Acum[c*GG + gid];
    const float e = Hend[c*GG + gid];
    Hend[c*GG + gid] = h;                         // h_in for chunk c
    h = fmaf(a, h, e);
  }
}

// Pass C: re-run each chunk from its true h_in, emit y (reduced over the 16 states).
__global__ __launch_bounds__(256) void k_scanC(const float* __restrict__ delta,
    const float* __restrict__ xh, const float* __restrict__ Bm,
    const float* __restrict__ Cm, const void* alogs, const int* flagp,
    const float* __restrict__ Hin, float* __restrict__ ybuf){
  const int bf = *flagp;
  const int blk = blockIdx.x;          // 3072
  const int c = blk & (NC-1);
  const int r = blk >> 4;
  const int dblk = r % 24;
  const int k = (r / 24) & 3;
  const int b = r / 96;
  const int t = threadIdx.x;
  const int d = dblk*16 + (t >> 4);
  const int n = t & 15;
  const float An = -__expf(ldin(alogs, (k*DI + d)*NS + n, bf));
  const int dbase  = ((b*KK+k)*LL)*DI + d;
  const int bcbase = ((b*KK+k)*LL)*NS + n;
  const int xbase  = b*LL*DI + d;
  const int gid = ((b*KK + k)*DI + d)*NS + n;
  float h = Hin[c*GG + gid];
  const int l0 = c*LC;
  #pragma unroll 4
  for (int l = l0; l < l0+LC; l++){
    const float dl = delta[dbase + l*DI];
    const float u  = xh[xbase + permk(k,l)*DI];
    const float Bn = Bm[bcbase + l*NS];
    const float Cn = Cm[bcbase + l*NS];
    const float dA = __expf(dl * An);
    h = fmaf(dA, h, dl*u*Bn);
    float p = h * Cn;
    p += __shfl_xor(p, 1, 16);
    p += __shfl_xor(p, 2, 16);
    p += __shfl_xor(p, 4, 16);
    p += __shfl_xor(p, 8, 16);
    if (n == 0) ybuf[dbase + l*DI] = p;
  }
}

// merge 4 directions (+D*u folded to xh * sum_k Ds) + LayerNorm + SiLU(z) gate + out-proj
__global__ __launch_bounds__(256) void k_merge(const float* __restrict__ scanY,
    const float* __restrict__ xh, const float* __restrict__ z,
    const void* dsP, const void* gP, const void* bP, const void* woP,
    const int* flagp, void* out){
  const int bf = *flagp;
  const int blk = blockIdx.x;          // B*L = 2048
  const int b = blk >> 10;
  const int l = blk & 1023;
  const int h = l >> 5, w = l & 31;
  const int lt = w*32 + h;
  const int t = threadIdx.x;
  __shared__ float yb[DI];
  __shared__ float stats[2];
  __shared__ float wred[4], wred2[4];
  float s = 0.f, s2 = 0.f;
  for (int d=t; d<DI; d+=256){
    float y = scanY[((b*KK+0)*LL + l        )*DI + d]
            + scanY[((b*KK+2)*LL + (LL-1-l ))*DI + d]
            + scanY[((b*KK+1)*LL + lt       )*DI + d]
            + scanY[((b*KK+3)*LL + (LL-1-lt))*DI + d];
    const float dsum = ldin(dsP, d, bf) + ldin(dsP, DI+d, bf)
                     + ldin(dsP, 2*DI+d, bf) + ldin(dsP, 3*DI+d, bf);
    y = fmaf(xh[(b*LL+l)*DI + d], dsum, y);
    yb[d] = y;
    s += y; s2 = fmaf(y, y, s2);
  }
  #pragma unroll
  for (int m=32;m>=1;m>>=1){ s += __shfl_down(s, m); s2 += __shfl_down(s2, m); }
  if ((t & 63) == 0){ wred[t>>6] = s; wred2[t>>6] = s2; }
  __syncthreads();
  if (t == 0){
    float a=0.f, c=0.f;
    #pragma unroll
    for (int i=0;i<4;i++){ a += wred[i]; c += wred2[i]; }
    const float mu = a / DI;
    const float var = fmaxf(c / DI - mu*mu, 0.f);
    stats[0] = mu;
    stats[1] = rsqrtf(var + 1e-5f);
  }
  __syncthreads();
  const float mu = stats[0], rs = stats[1];
  for (int d=t; d<DI; d+=256){
    float yn = (yb[d]-mu)*rs*ldin(gP, d, bf) + ldin(bP, d, bf);
    const float zg = z[(b*LL+l)*DI + d];
    yb[d] = yn * zg * sigm(zg);
  }
  __syncthreads();
  if (t < DM){
    float acc = 0.f;
    const int wbase = t*DI;
    for (int d=0; d<DI; d+=4){
      float4 wv = ldin4(woP, wbase+d, bf);
      float4 yv = *(const float4*)&yb[d];
      acc = fmaf(wv.x, yv.x, acc);
      acc = fmaf(wv.y, yv.y, acc);
      acc = fmaf(wv.z, yv.z, acc);
      acc = fmaf(wv.w, yv.w, acc);
    }
    if (bf) ((__hip_bfloat16*)out)[(b*LL+l)*DM + t] = __float2bfloat16(acc);
    else    ((float*)out)[(b*LL+l)*DM + t] = acc;
  }
}

extern "C" void kernel_launch(void* const* d_in, const int* in_sizes, int n_in,
                              void* d_out, int out_size, void* d_ws, size_t ws_size,
                              hipStream_t stream){
  const void* x    = d_in[0];
  const void* xcr  = d_in[1];
  const void* wi   = d_in[2];
  const void* wc   = d_in[3];
  const void* cw   = d_in[4];
  const void* cb   = d_in[5];
  const void* xpw  = d_in[6];
  const void* dtw  = d_in[7];
  const void* dtb  = d_in[8];
  const void* alog = d_in[9];
  const void* dsv  = d_in[10];
  const void* gno  = d_in[11];
  const void* bno  = d_in[12];
  const void* wo   = d_in[13];

  float* ws = (float*)d_ws;
  int*   flag = (int*)ws;
  float* xp    = ws + 16;
  float* z     = xp    + (size_t)BB*LL*DI;
  float* xc    = z     + (size_t)BB*LL*DI;
  float* xh    = xc    + (size_t)BB*LL*DI;
  float* delta = xh    + (size_t)BB*LL*DI;
  float* Bm    = delta + (size_t)BB*KK*LL*DI;
  float* Cm    = Bm    + (size_t)BB*KK*LL*NS;
  float* Acum  = Cm    + (size_t)BB*KK*LL*NS;
  float* Hend  = Acum  + (size_t)GG*NC;
  float* ybuf  = Hend  + (size_t)GG*NC;
  // total ~64 MB of fp32 scratch

  k_detect<<<1, 1, 0, stream>>>((const unsigned*)dsv, flag);
  k_inproj<<<3*256, 256, 0, stream>>>(x, xcr, wi, wc, flag, xp, z, xc);
  k_conv  <<<BB*LL*DI/256, 256, 0, stream>>>(xp, cw, cb, flag, xh);
  k_xproj <<<BB*KK*LL, 64, 0, stream>>>(xc, xpw, dtw, dtb, flag, delta, Bm, Cm);
  k_scanA <<<BB*KK*24*NC, 256, 0, stream>>>(delta, xh, Bm, alog, flag, Acum, Hend);
  k_scanB <<<GG/256, 256, 0, stream>>>(Acum, Hend);
  k_scanC <<<BB*KK*24*NC, 256, 0, stream>>>(delta, xh, Bm, Cm, alog, flag, Hend, ybuf);
  k_merge <<<BB*LL, 256, 0, stream>>>(ybuf, xh, z, dsv, gno, bno, wo, flag, d_out);
}

// Round 3
// 315.815 us; speedup vs baseline: 4.1898x; 1.2895x over previous
//
#include <hip/hip_runtime.h>
#include <hip/hip_bf16.h>
#include <math.h>

#define BB 2
#define HH 32
#define WW 32
#define LL 1024
#define DM 192
#define DI 384
#define NS 16
#define RR 12
#define KK 4
#define CC 44   /* RR + 2*NS */
#define NC 16   /* scan chunks */
#define LC 64   /* chunk length */
#define GG 196608  /* B*K*DI*NS */

// ---- dtype-flex loads (flag: 0=fp32, 1=bf16), decided on-device from Ds[0] ----
__device__ __forceinline__ float ldin(const void* p, int i, int bf) {
  if (bf) {
    unsigned v = ((const unsigned short*)p)[i];
    return __uint_as_float(v << 16);
  }
  return ((const float*)p)[i];
}
// 4-wide flex load; i must be a multiple of 4
__device__ __forceinline__ float4 ldin4(const void* p, int i, int bf) {
  if (bf) {
    ushort4 u = ((const ushort4*)p)[i >> 2];
    float4 r;
    r.x = __uint_as_float((unsigned)u.x << 16);
    r.y = __uint_as_float((unsigned)u.y << 16);
    r.z = __uint_as_float((unsigned)u.z << 16);
    r.w = __uint_as_float((unsigned)u.w << 16);
    return r;
  }
  return ((const float4*)p)[i >> 2];
}
__device__ __forceinline__ float sigm(float x){ return 1.f/(1.f + __expf(-x)); }
__device__ __forceinline__ float softplusf(float x){ return (x > 20.f) ? x : log1pf(__expf(x)); }

// scan-index -> physical (row-major h*W+w) index for direction k
__device__ __forceinline__ int permk(int k, int l){
  if (k == 0) return l;
  if (k == 2) return LL-1-l;
  int lr = (k == 3) ? (LL-1-l) : l;
  return (lr & 31)*WW + (lr >> 5);   // (l%H)*W + (l/H)
}

__global__ void k_detect(const unsigned* ds, int* flag){
  *flag = (*ds == 0x3F800000u) ? 0 : 1;   // fp32 ones vs bf16 pair 0x3F803F80
}

// in-projections: 16 positions per block, 2 output rows per thread (32 FMA chains
// per weight-pair load). grid = 3 row-groups x 128 tiles, block = 192 (3 waves).
__global__ __launch_bounds__(192) void k_inproj(const void* x, const void* xcr,
    const void* wi, const void* wc, const int* flagp,
    float* __restrict__ xp, float* __restrict__ z, float* __restrict__ xc){
  const int bf = *flagp;
  __shared__ float xs_[16][DM];
  const int t = threadIdx.x;
  const int rg = blockIdx.x / 128;           // 0: xp rows, 1: z rows, 2: xc rows
  const int pos0 = (blockIdx.x % 128) * 16;
  const void* src = (rg == 2) ? xcr : x;
  for (int i = t*4; i < 16*DM; i += 192*4) {
    float4 v = ldin4(src, pos0*DM + i, bf);
    *(float4*)&(((float*)xs_)[i]) = v;
  }
  __syncthreads();
  const void* wb = (rg == 2) ? wc : wi;
  const int rbase = (rg == 1) ? 384 : 0;
  float* dst = (rg == 0) ? xp : (rg == 1 ? z : xc);
  const int o1 = t, o2 = t + 192;
  float acc1[16], acc2[16];
  #pragma unroll
  for (int p=0;p<16;p++){ acc1[p]=0.f; acc2[p]=0.f; }
  for (int j=0;j<DM;j+=4) {
    const float4 w1 = ldin4(wb, (rbase+o1)*DM + j, bf);
    const float4 w2 = ldin4(wb, (rbase+o2)*DM + j, bf);
    #pragma unroll
    for (int p=0;p<16;p++){
      const float4 xv = *(const float4*)&xs_[p][j];
      acc1[p] = fmaf(w1.x, xv.x, acc1[p]);
      acc1[p] = fmaf(w1.y, xv.y, acc1[p]);
      acc1[p] = fmaf(w1.z, xv.z, acc1[p]);
      acc1[p] = fmaf(w1.w, xv.w, acc1[p]);
      acc2[p] = fmaf(w2.x, xv.x, acc2[p]);
      acc2[p] = fmaf(w2.y, xv.y, acc2[p]);
      acc2[p] = fmaf(w2.z, xv.z, acc2[p]);
      acc2[p] = fmaf(w2.w, xv.w, acc2[p]);
    }
  }
  #pragma unroll
  for (int p=0;p<16;p++){
    dst[(pos0+p)*DI + o1] = acc1[p];
    dst[(pos0+p)*DI + o2] = acc2[p];
  }
}

// depthwise 3x3 conv + bias + SiLU; layout [b, l(=h*W+w), d]
__global__ __launch_bounds__(256) void k_conv(const float* __restrict__ xp,
    const void* cw, const void* cb, const int* flagp, float* __restrict__ xh){
  const int bf = *flagp;
  const int idx = blockIdx.x*256 + threadIdx.x;    // B*L*DI = 786432 exact
  const int d = idx % DI;
  const int l = (idx / DI) % LL;
  const int b = idx / (DI*LL);
  const int h = l >> 5, w = l & 31;
  float acc = ldin(cb, d, bf);
  #pragma unroll
  for (int kh=0; kh<3; kh++){
    const int hh = h + kh - 1;
    if (hh < 0 || hh >= HH) continue;
    #pragma unroll
    for (int kw=0; kw<3; kw++){
      const int ww2 = w + kw - 1;
      if (ww2 < 0 || ww2 >= WW) continue;
      acc = fmaf(xp[(b*LL + hh*WW + ww2)*DI + d], ldin(cw, d*9 + kh*3 + kw, bf), acc);
    }
  }
  xh[idx] = acc * sigm(acc);
}

// x_proj + dt_proj for 16 positions per block. grid = B*K*64 = 512 blocks.
__global__ __launch_bounds__(256) void k_xproj(const float* __restrict__ xc, const void* xpw,
    const void* dtw, const void* dtb, const int* flagp,
    float* __restrict__ delta, float* __restrict__ Bm, float* __restrict__ Cm){
  const int bf = *flagp;
  const int blk = blockIdx.x;          // 512
  const int b = blk >> 8;
  const int k = (blk >> 6) & 3;
  const int l0 = (blk & 63) * 16;
  const int t = threadIdx.x;
  __shared__ float xrow[16][DI+4];     // pad 4 floats: 16-pos column reads -> 2-way max
  __shared__ float dtwS[DI][13];       // pad to 13: stride-12 would be 8-way conflict
  __shared__ float dtsS[16][RR];
  // stage the 16 permuted activation rows
  for (int idx = t; idx < 16*96; idx += 256){
    const int j = idx / 96, c = idx % 96;
    const int pl = permk(k, l0 + j);
    *(float4*)&xrow[j][c*4] = *(const float4*)&xc[(b*LL + pl)*DI + c*4];
  }
  // stage dt_projs_weight[k] (384x12)
  for (int idx = t; idx < DI*RR; idx += 256){
    const int d = idx / RR, r = idx % RR;
    dtwS[d][r] = ldin(dtw, (k*DI + d)*RR + r, bf);
  }
  __syncthreads();
  // x_dbl: 44 channels x 16 positions
  for (int idx = t; idx < CC*16; idx += 256){
    const int ch = idx >> 4, j = idx & 15;
    float acc = 0.f;
    const int wbase = (k*CC + ch)*DI;
    for (int c = 0; c < 96; c++){
      const float4 wv = ldin4(xpw, wbase + c*4, bf);
      const float4 xv = *(const float4*)&xrow[j][c*4];
      acc = fmaf(wv.x, xv.x, acc);
      acc = fmaf(wv.y, xv.y, acc);
      acc = fmaf(wv.z, xv.z, acc);
      acc = fmaf(wv.w, xv.w, acc);
    }
    if (ch < RR)           dtsS[j][ch] = acc;
    else if (ch < RR+NS)   Bm[((b*KK+k)*LL + l0+j)*NS + (ch-RR)]    = acc;
    else                   Cm[((b*KK+k)*LL + l0+j)*NS + (ch-RR-NS)] = acc;
  }
  __syncthreads();
  // dt_proj + softplus -> delta (d-coalesced stores)
  for (int idx = t; idx < 16*DI; idx += 256){
    const int j = idx / DI, d = idx % DI;
    float acc = ldin(dtb, k*DI + d, bf);
    #pragma unroll
    for (int r = 0; r < RR; r++) acc = fmaf(dtwS[d][r], dtsS[j][r], acc);
    delta[((b*KK+k)*LL + l0+j)*DI + d] = softplusf(acc);
  }
}

// ---- chunked selective scan, 3 passes ----
__global__ __launch_bounds__(256) void k_scanA(const float* __restrict__ delta,
    const float* __restrict__ xh, const float* __restrict__ Bm,
    const void* alogs, const int* flagp,
    float* __restrict__ Acum, float* __restrict__ Hend){
  const int bf = *flagp;
  const int blk = blockIdx.x;          // B*K*24*NC = 3072
  const int c = blk & (NC-1);
  const int r = blk >> 4;
  const int dblk = r % 24;
  const int k = (r / 24) & 3;
  const int b = r / 96;
  const int t = threadIdx.x;
  const int d = dblk*16 + (t >> 4);
  const int n = t & 15;
  const float An = -__expf(ldin(alogs, (k*DI + d)*NS + n, bf));
  const int dbase  = ((b*KK+k)*LL)*DI + d;
  const int bcbase = ((b*KK+k)*LL)*NS + n;
  const int xbase  = b*LL*DI + d;
  float h = 0.f, Ac = 1.f;
  const int l0 = c*LC;
  #pragma unroll 4
  for (int l = l0; l < l0+LC; l++){
    const float dl = delta[dbase + l*DI];
    const float u  = xh[xbase + permk(k,l)*DI];
    const float Bn = Bm[bcbase + l*NS];
    const float dA = __expf(dl * An);
    Ac *= dA;
    h = fmaf(dA, h, dl*u*Bn);
  }
  const int gid = ((b*KK + k)*DI + d)*NS + n;
  Acum[c*GG + gid] = Ac;
  Hend[c*GG + gid] = h;
}

__global__ __launch_bounds__(256) void k_scanB(const float* __restrict__ Acum,
    float* __restrict__ Hend){
  const int gid = blockIdx.x*256 + threadIdx.x;   // GG threads
  float h = 0.f;
  #pragma unroll
  for (int c = 0; c < NC; c++){
    const float a = Acum[c*GG + gid];
    const float e = Hend[c*GG + gid];
    Hend[c*GG + gid] = h;                         // h_in for chunk c
    h = fmaf(a, h, e);
  }
}

__global__ __launch_bounds__(256) void k_scanC(const float* __restrict__ delta,
    const float* __restrict__ xh, const float* __restrict__ Bm,
    const float* __restrict__ Cm, const void* alogs, const int* flagp,
    const float* __restrict__ Hin, float* __restrict__ ybuf){
  const int bf = *flagp;
  const int blk = blockIdx.x;          // 3072
  const int c = blk & (NC-1);
  const int r = blk >> 4;
  const int dblk = r % 24;
  const int k = (r / 24) & 3;
  const int b = r / 96;
  const int t = threadIdx.x;
  const int d = dblk*16 + (t >> 4);
  const int n = t & 15;
  const float An = -__expf(ldin(alogs, (k*DI + d)*NS + n, bf));
  const int dbase  = ((b*KK+k)*LL)*DI + d;
  const int bcbase = ((b*KK+k)*LL)*NS + n;
  const int xbase  = b*LL*DI + d;
  const int gid = ((b*KK + k)*DI + d)*NS + n;
  float h = Hin[c*GG + gid];
  const int l0 = c*LC;
  #pragma unroll 4
  for (int l = l0; l < l0+LC; l++){
    const float dl = delta[dbase + l*DI];
    const float u  = xh[xbase + permk(k,l)*DI];
    const float Bn = Bm[bcbase + l*NS];
    const float Cn = Cm[bcbase + l*NS];
    const float dA = __expf(dl * An);
    h = fmaf(dA, h, dl*u*Bn);
    float p = h * Cn;
    p += __shfl_xor(p, 1, 16);
    p += __shfl_xor(p, 2, 16);
    p += __shfl_xor(p, 4, 16);
    p += __shfl_xor(p, 8, 16);
    if (n == 0) ybuf[dbase + l*DI] = p;
  }
}

// merge + LN (wave-per-position butterfly, no barriers) + gate + out-proj
// 8 positions per block; out-proj weights amortized 8x with 8 FMA chains/thread.
__global__ __launch_bounds__(256) void k_merge(const float* __restrict__ scanY,
    const float* __restrict__ xh, const float* __restrict__ z,
    const void* dsP, const void* gP, const void* bP, const void* woP,
    const int* flagp, void* out){
  const int bf = *flagp;
  const int blk = blockIdx.x;          // 256
  const int t = threadIdx.x;
  const int wv = t >> 6, lane = t & 63;
  __shared__ float ygs[8][DI];
  #pragma unroll
  for (int rep = 0; rep < 2; rep++){
    const int j = wv*2 + rep;
    const int pos = blk*8 + j;
    const int b = pos >> 10, l = pos & 1023;
    const int lt = (l & 31)*32 + (l >> 5);
    float yv[6];
    float s = 0.f, s2 = 0.f;
    #pragma unroll
    for (int i = 0; i < 6; i++){
      const int d = i*64 + lane;
      float y = scanY[((b*KK+0)*LL + l        )*DI + d]
              + scanY[((b*KK+2)*LL + (LL-1-l ))*DI + d]
              + scanY[((b*KK+1)*LL + lt       )*DI + d]
              + scanY[((b*KK+3)*LL + (LL-1-lt))*DI + d];
      const float dsum = ldin(dsP, d, bf) + ldin(dsP, DI+d, bf)
                       + ldin(dsP, 2*DI+d, bf) + ldin(dsP, 3*DI+d, bf);
      y = fmaf(xh[(b*LL+l)*DI + d], dsum, y);
      yv[i] = y;
      s += y; s2 = fmaf(y, y, s2);
    }
    #pragma unroll
    for (int m = 1; m < 64; m <<= 1){
      s  += __shfl_xor(s,  m);
      s2 += __shfl_xor(s2, m);
    }
    const float mu = s * (1.f/DI);
    const float var = fmaxf(s2 * (1.f/DI) - mu*mu, 0.f);
    const float rs = rsqrtf(var + 1e-5f);
    #pragma unroll
    for (int i = 0; i < 6; i++){
      const int d = i*64 + lane;
      const float yn = (yv[i]-mu)*rs*ldin(gP, d, bf) + ldin(bP, d, bf);
      const float zg = z[(b*LL+l)*DI + d];
      ygs[j][d] = yn * zg * sigm(zg);
    }
  }
  __syncthreads();
  if (t < DM){
    const int o = t;
    float acc[8];
    #pragma unroll
    for (int j=0;j<8;j++) acc[j] = 0.f;
    for (int c = 0; c < 96; c++){
      const float4 w4 = ldin4(woP, o*DI + c*4, bf);
      #pragma unroll
      for (int j=0;j<8;j++){
        const float4 y4 = *(const float4*)&ygs[j][c*4];
        acc[j] = fmaf(w4.x, y4.x, acc[j]);
        acc[j] = fmaf(w4.y, y4.y, acc[j]);
        acc[j] = fmaf(w4.z, y4.z, acc[j]);
        acc[j] = fmaf(w4.w, y4.w, acc[j]);
      }
    }
    #pragma unroll
    for (int j=0;j<8;j++){
      const int pos = blk*8 + j;
      if (bf) ((__hip_bfloat16*)out)[pos*DM + o] = __float2bfloat16(acc[j]);
      else    ((float*)out)[pos*DM + o] = acc[j];
    }
  }
}

extern "C" void kernel_launch(void* const* d_in, const int* in_sizes, int n_in,
                              void* d_out, int out_size, void* d_ws, size_t ws_size,
                              hipStream_t stream){
  const void* x    = d_in[0];
  const void* xcr  = d_in[1];
  const void* wi   = d_in[2];
  const void* wc   = d_in[3];
  const void* cw   = d_in[4];
  const void* cb   = d_in[5];
  const void* xpw  = d_in[6];
  const void* dtw  = d_in[7];
  const void* dtb  = d_in[8];
  const void* alog = d_in[9];
  const void* dsv  = d_in[10];
  const void* gno  = d_in[11];
  const void* bno  = d_in[12];
  const void* wo   = d_in[13];

  float* ws = (float*)d_ws;
  int*   flag = (int*)ws;
  float* xp    = ws + 16;
  float* z     = xp    + (size_t)BB*LL*DI;
  float* xc    = z     + (size_t)BB*LL*DI;
  float* xh    = xc    + (size_t)BB*LL*DI;
  float* delta = xh    + (size_t)BB*LL*DI;
  float* Bm    = delta + (size_t)BB*KK*LL*DI;
  float* Cm    = Bm    + (size_t)BB*KK*LL*NS;
  float* Acum  = Cm    + (size_t)BB*KK*LL*NS;
  float* Hend  = Acum  + (size_t)GG*NC;
  float* ybuf  = Hend  + (size_t)GG*NC;

  k_detect<<<1, 1, 0, stream>>>((const unsigned*)dsv, flag);
  k_inproj<<<3*128, 192, 0, stream>>>(x, xcr, wi, wc, flag, xp, z, xc);
  k_conv  <<<BB*LL*DI/256, 256, 0, stream>>>(xp, cw, cb, flag, xh);
  k_xproj <<<BB*KK*64, 256, 0, stream>>>(xc, xpw, dtw, dtb, flag, delta, Bm, Cm);
  k_scanA <<<BB*KK*24*NC, 256, 0, stream>>>(delta, xh, Bm, alog, flag, Acum, Hend);
  k_scanB <<<GG/256, 256, 0, stream>>>(Acum, Hend);
  k_scanC <<<BB*KK*24*NC, 256, 0, stream>>>(delta, xh, Bm, Cm, alog, flag, Hend, ybuf);
  k_merge <<<BB*LL/8, 256, 0, stream>>>(ybuf, xh, z, dsv, gno, bno, wo, flag, d_out);
}

// Round 4
// 261.633 us; speedup vs baseline: 5.0575x; 1.2071x over previous
//
#include <hip/hip_runtime.h>
#include <hip/hip_bf16.h>
#include <math.h>

#define BB 2
#define HH 32
#define WW 32
#define LL 1024
#define DM 192
#define DI 384
#define NS 16
#define RR 12
#define KK 4
#define CC 44    /* RR + 2*NS */
#define NC 64    /* scan chunks */
#define LC 16    /* chunk length */
#define NCH 3072 /* B*K*DI chains */
#define GB 49152 /* NCH * NS */

// ---- dtype-flex loads (flag: 0=fp32, 1=bf16), decided on-device from Ds[0] ----
__device__ __forceinline__ float ldin(const void* p, int i, int bf) {
  if (bf) {
    unsigned v = ((const unsigned short*)p)[i];
    return __uint_as_float(v << 16);
  }
  return ((const float*)p)[i];
}
// 4-wide flex load; i must be a multiple of 4
__device__ __forceinline__ float4 ldin4(const void* p, int i, int bf) {
  if (bf) {
    ushort4 u = ((const ushort4*)p)[i >> 2];
    float4 r;
    r.x = __uint_as_float((unsigned)u.x << 16);
    r.y = __uint_as_float((unsigned)u.y << 16);
    r.z = __uint_as_float((unsigned)u.z << 16);
    r.w = __uint_as_float((unsigned)u.w << 16);
    return r;
  }
  return ((const float4*)p)[i >> 2];
}
__device__ __forceinline__ float sigm(float x){ return 1.f/(1.f + __expf(-x)); }
__device__ __forceinline__ float softplusf(float x){ return (x > 20.f) ? x : log1pf(__expf(x)); }

// scan-index -> physical (row-major h*W+w) index for direction k
__device__ __forceinline__ int permk(int k, int l){
  if (k == 0) return l;
  if (k == 2) return LL-1-l;
  int lr = (k == 3) ? (LL-1-l) : l;
  return (lr & 31)*WW + (lr >> 5);   // (l%H)*W + (l/H)
}

__global__ void k_detect(const unsigned* ds, int* flag){
  *flag = (*ds == 0x3F800000u) ? 0 : 1;   // fp32 ones vs bf16 pair 0x3F803F80
}

// in-projections: 16 positions per block, 2 output rows per thread (32 FMA chains
// per weight-pair load). grid = 3 row-groups x 128 tiles, block = 192 (3 waves).
__global__ __launch_bounds__(192) void k_inproj(const void* x, const void* xcr,
    const void* wi, const void* wc, const int* flagp,
    float* __restrict__ xp, float* __restrict__ z, float* __restrict__ xc){
  const int bf = *flagp;
  __shared__ float xs_[16][DM];
  const int t = threadIdx.x;
  const int rg = blockIdx.x / 128;           // 0: xp rows, 1: z rows, 2: xc rows
  const int pos0 = (blockIdx.x % 128) * 16;
  const void* src = (rg == 2) ? xcr : x;
  for (int i = t*4; i < 16*DM; i += 192*4) {
    float4 v = ldin4(src, pos0*DM + i, bf);
    *(float4*)&(((float*)xs_)[i]) = v;
  }
  __syncthreads();
  const void* wb = (rg == 2) ? wc : wi;
  const int rbase = (rg == 1) ? 384 : 0;
  float* dst = (rg == 0) ? xp : (rg == 1 ? z : xc);
  const int o1 = t, o2 = t + 192;
  float acc1[16], acc2[16];
  #pragma unroll
  for (int p=0;p<16;p++){ acc1[p]=0.f; acc2[p]=0.f; }
  for (int j=0;j<DM;j+=4) {
    const float4 w1 = ldin4(wb, (rbase+o1)*DM + j, bf);
    const float4 w2 = ldin4(wb, (rbase+o2)*DM + j, bf);
    #pragma unroll
    for (int p=0;p<16;p++){
      const float4 xv = *(const float4*)&xs_[p][j];
      acc1[p] = fmaf(w1.x, xv.x, acc1[p]);
      acc1[p] = fmaf(w1.y, xv.y, acc1[p]);
      acc1[p] = fmaf(w1.z, xv.z, acc1[p]);
      acc1[p] = fmaf(w1.w, xv.w, acc1[p]);
      acc2[p] = fmaf(w2.x, xv.x, acc2[p]);
      acc2[p] = fmaf(w2.y, xv.y, acc2[p]);
      acc2[p] = fmaf(w2.z, xv.z, acc2[p]);
      acc2[p] = fmaf(w2.w, xv.w, acc2[p]);
    }
  }
  #pragma unroll
  for (int p=0;p<16;p++){
    dst[(pos0+p)*DI + o1] = acc1[p];
    dst[(pos0+p)*DI + o2] = acc2[p];
  }
}

// depthwise 3x3 conv + bias + SiLU; layout [b, l(=h*W+w), d]
__global__ __launch_bounds__(256) void k_conv(const float* __restrict__ xp,
    const void* cw, const void* cb, const int* flagp, float* __restrict__ xh){
  const int bf = *flagp;
  const int idx = blockIdx.x*256 + threadIdx.x;    // B*L*DI = 786432 exact
  const int d = idx % DI;
  const int l = (idx / DI) % LL;
  const int b = idx / (DI*LL);
  const int h = l >> 5, w = l & 31;
  float acc = ldin(cb, d, bf);
  #pragma unroll
  for (int kh=0; kh<3; kh++){
    const int hh = h + kh - 1;
    if (hh < 0 || hh >= HH) continue;
    #pragma unroll
    for (int kw=0; kw<3; kw++){
      const int ww2 = w + kw - 1;
      if (ww2 < 0 || ww2 >= WW) continue;
      acc = fmaf(xp[(b*LL + hh*WW + ww2)*DI + d], ldin(cw, d*9 + kh*3 + kw, bf), acc);
    }
  }
  xh[idx] = acc * sigm(acc);
}

// x_proj + dt_proj for 16 positions per block. grid = B*K*64 = 512 blocks.
__global__ __launch_bounds__(256) void k_xproj(const float* __restrict__ xc, const void* xpw,
    const void* dtw, const void* dtb, const int* flagp,
    float* __restrict__ delta, float* __restrict__ Bm, float* __restrict__ Cm){
  const int bf = *flagp;
  const int blk = blockIdx.x;          // 512
  const int b = blk >> 8;
  const int k = (blk >> 6) & 3;
  const int l0 = (blk & 63) * 16;
  const int t = threadIdx.x;
  __shared__ float xrow[16][DI+4];     // pad 4 floats: 16-pos column reads -> 2-way max
  __shared__ float dtwS[DI][13];       // pad to 13: stride-12 would be 8-way conflict
  __shared__ float dtsS[16][RR];
  // stage the 16 permuted activation rows
  for (int idx = t; idx < 16*96; idx += 256){
    const int j = idx / 96, c = idx % 96;
    const int pl = permk(k, l0 + j);
    *(float4*)&xrow[j][c*4] = *(const float4*)&xc[(b*LL + pl)*DI + c*4];
  }
  // stage dt_projs_weight[k] (384x12)
  for (int idx = t; idx < DI*RR; idx += 256){
    const int d = idx / RR, r = idx % RR;
    dtwS[d][r] = ldin(dtw, (k*DI + d)*RR + r, bf);
  }
  __syncthreads();
  // x_dbl: 44 channels x 16 positions
  for (int idx = t; idx < CC*16; idx += 256){
    const int ch = idx >> 4, j = idx & 15;
    float acc = 0.f;
    const int wbase = (k*CC + ch)*DI;
    for (int c = 0; c < 96; c++){
      const float4 wv = ldin4(xpw, wbase + c*4, bf);
      const float4 xv = *(const float4*)&xrow[j][c*4];
      acc = fmaf(wv.x, xv.x, acc);
      acc = fmaf(wv.y, xv.y, acc);
      acc = fmaf(wv.z, xv.z, acc);
      acc = fmaf(wv.w, xv.w, acc);
    }
    if (ch < RR)           dtsS[j][ch] = acc;
    else if (ch < RR+NS)   Bm[((b*KK+k)*LL + l0+j)*NS + (ch-RR)]    = acc;
    else                   Cm[((b*KK+k)*LL + l0+j)*NS + (ch-RR-NS)] = acc;
  }
  __syncthreads();
  // dt_proj + softplus -> delta (d-coalesced stores)
  for (int idx = t; idx < 16*DI; idx += 256){
    const int j = idx / DI, d = idx % DI;
    float acc = ldin(dtb, k*DI + d, bf);
    #pragma unroll
    for (int r = 0; r < RR; r++) acc = fmaf(dtwS[d][r], dtsS[j][r], acc);
    delta[((b*KK+k)*LL + l0+j)*DI + d] = softplusf(acc);
  }
}

// ---- chunked selective scan, 3 passes; one thread owns a whole chain segment
// (all 16 states in registers). lanes cover 64 consecutive d -> coalesced. ----
__global__ __launch_bounds__(256) void k_scanA(const float* __restrict__ delta,
    const float* __restrict__ xh, const float* __restrict__ Bm,
    const void* alogs, const int* flagp,
    float* __restrict__ Acum, float* __restrict__ Hend){
  const int bf = *flagp;
  const int c = blockIdx.x / 12;              // chunk (uniform per block)
  const int chain = (blockIdx.x % 12)*256 + threadIdx.x;   // (b*K+k)*DI + d
  const int d = chain % DI;
  const int k = (chain / DI) & 3;
  const int b = chain / (DI*KK);
  float An[NS];
  #pragma unroll
  for (int q = 0; q < 4; q++){
    const float4 a4 = ldin4(alogs, (k*DI + d)*NS + q*4, bf);
    An[q*4+0] = -__expf(a4.x); An[q*4+1] = -__expf(a4.y);
    An[q*4+2] = -__expf(a4.z); An[q*4+3] = -__expf(a4.w);
  }
  float h[NS], Ac[NS];
  #pragma unroll
  for (int n = 0; n < NS; n++){ h[n] = 0.f; Ac[n] = 1.f; }
  const int lb = (b*KK+k)*LL;
  const int xbase = b*LL*DI + d;
  const int l0 = c*LC;
  #pragma unroll 4
  for (int l = l0; l < l0+LC; l++){
    const float dl = delta[(lb + l)*DI + d];
    const float u  = xh[xbase + permk(k,l)*DI];
    const float dlu = dl*u;
    const float4 B0 = *(const float4*)&Bm[(lb+l)*NS + 0];
    const float4 B1 = *(const float4*)&Bm[(lb+l)*NS + 4];
    const float4 B2 = *(const float4*)&Bm[(lb+l)*NS + 8];
    const float4 B3 = *(const float4*)&Bm[(lb+l)*NS + 12];
    const float Bv[NS] = {B0.x,B0.y,B0.z,B0.w, B1.x,B1.y,B1.z,B1.w,
                          B2.x,B2.y,B2.z,B2.w, B3.x,B3.y,B3.z,B3.w};
    #pragma unroll
    for (int n = 0; n < NS; n++){
      const float e = __expf(dl*An[n]);
      Ac[n] *= e;
      h[n] = fmaf(e, h[n], dlu*Bv[n]);
    }
  }
  const int obase = (c*NCH + chain)*NS;
  #pragma unroll
  for (int q = 0; q < 4; q++){
    *(float4*)&Acum[obase + q*4] = make_float4(Ac[q*4],Ac[q*4+1],Ac[q*4+2],Ac[q*4+3]);
    *(float4*)&Hend[obase + q*4] = make_float4(h[q*4],h[q*4+1],h[q*4+2],h[q*4+3]);
  }
}

__global__ __launch_bounds__(256) void k_scanB(const float* __restrict__ Acum,
    float* __restrict__ Hend){
  const int g = blockIdx.x*256 + threadIdx.x;   // GB = 49152 threads
  float h = 0.f;
  #pragma unroll 8
  for (int c = 0; c < NC; c++){
    const float a = Acum[c*GB + g];
    const float e = Hend[c*GB + g];
    Hend[c*GB + g] = h;                         // h_in for chunk c
    h = fmaf(a, h, e);
  }
}

__global__ __launch_bounds__(256) void k_scanC(const float* __restrict__ delta,
    const float* __restrict__ xh, const float* __restrict__ Bm,
    const float* __restrict__ Cm, const void* alogs, const int* flagp,
    const float* __restrict__ Hin, float* __restrict__ ybuf){
  const int bf = *flagp;
  const int c = blockIdx.x / 12;
  const int chain = (blockIdx.x % 12)*256 + threadIdx.x;
  const int d = chain % DI;
  const int k = (chain / DI) & 3;
  const int b = chain / (DI*KK);
  float An[NS];
  #pragma unroll
  for (int q = 0; q < 4; q++){
    const float4 a4 = ldin4(alogs, (k*DI + d)*NS + q*4, bf);
    An[q*4+0] = -__expf(a4.x); An[q*4+1] = -__expf(a4.y);
    An[q*4+2] = -__expf(a4.z); An[q*4+3] = -__expf(a4.w);
  }
  float h[NS];
  const int ibase = (c*NCH + chain)*NS;
  #pragma unroll
  for (int q = 0; q < 4; q++){
    const float4 h4 = *(const float4*)&Hin[ibase + q*4];
    h[q*4+0]=h4.x; h[q*4+1]=h4.y; h[q*4+2]=h4.z; h[q*4+3]=h4.w;
  }
  const int lb = (b*KK+k)*LL;
  const int xbase = b*LL*DI + d;
  const int l0 = c*LC;
  #pragma unroll 4
  for (int l = l0; l < l0+LC; l++){
    const float dl = delta[(lb + l)*DI + d];
    const float u  = xh[xbase + permk(k,l)*DI];
    const float dlu = dl*u;
    const float4 B0 = *(const float4*)&Bm[(lb+l)*NS + 0];
    const float4 B1 = *(const float4*)&Bm[(lb+l)*NS + 4];
    const float4 B2 = *(const float4*)&Bm[(lb+l)*NS + 8];
    const float4 B3 = *(const float4*)&Bm[(lb+l)*NS + 12];
    const float4 C0 = *(const float4*)&Cm[(lb+l)*NS + 0];
    const float4 C1 = *(const float4*)&Cm[(lb+l)*NS + 4];
    const float4 C2 = *(const float4*)&Cm[(lb+l)*NS + 8];
    const float4 C3 = *(const float4*)&Cm[(lb+l)*NS + 12];
    const float Bv[NS] = {B0.x,B0.y,B0.z,B0.w, B1.x,B1.y,B1.z,B1.w,
                          B2.x,B2.y,B2.z,B2.w, B3.x,B3.y,B3.z,B3.w};
    const float Cv[NS] = {C0.x,C0.y,C0.z,C0.w, C1.x,C1.y,C1.z,C1.w,
                          C2.x,C2.y,C2.z,C2.w, C3.x,C3.y,C3.z,C3.w};
    float y = 0.f;
    #pragma unroll
    for (int n = 0; n < NS; n++){
      const float e = __expf(dl*An[n]);
      h[n] = fmaf(e, h[n], dlu*Bv[n]);
      y = fmaf(h[n], Cv[n], y);
    }
    ybuf[(lb + l)*DI + d] = y;
  }
}

// merge + LN (wave-per-position butterfly, no barriers) + gate + out-proj
// 8 positions per block; out-proj weights amortized 8x with 8 FMA chains/thread.
__global__ __launch_bounds__(256) void k_merge(const float* __restrict__ scanY,
    const float* __restrict__ xh, const float* __restrict__ z,
    const void* dsP, const void* gP, const void* bP, const void* woP,
    const int* flagp, void* out){
  const int bf = *flagp;
  const int blk = blockIdx.x;          // 256
  const int t = threadIdx.x;
  const int wv = t >> 6, lane = t & 63;
  __shared__ float ygs[8][DI];
  #pragma unroll
  for (int rep = 0; rep < 2; rep++){
    const int j = wv*2 + rep;
    const int pos = blk*8 + j;
    const int b = pos >> 10, l = pos & 1023;
    const int lt = (l & 31)*32 + (l >> 5);
    float yv[6];
    float s = 0.f, s2 = 0.f;
    #pragma unroll
    for (int i = 0; i < 6; i++){
      const int d = i*64 + lane;
      float y = scanY[((b*KK+0)*LL + l        )*DI + d]
              + scanY[((b*KK+2)*LL + (LL-1-l ))*DI + d]
              + scanY[((b*KK+1)*LL + lt       )*DI + d]
              + scanY[((b*KK+3)*LL + (LL-1-lt))*DI + d];
      const float dsum = ldin(dsP, d, bf) + ldin(dsP, DI+d, bf)
                       + ldin(dsP, 2*DI+d, bf) + ldin(dsP, 3*DI+d, bf);
      y = fmaf(xh[(b*LL+l)*DI + d], dsum, y);
      yv[i] = y;
      s += y; s2 = fmaf(y, y, s2);
    }
    #pragma unroll
    for (int m = 1; m < 64; m <<= 1){
      s  += __shfl_xor(s,  m);
      s2 += __shfl_xor(s2, m);
    }
    const float mu = s * (1.f/DI);
    const float var = fmaxf(s2 * (1.f/DI) - mu*mu, 0.f);
    const float rs = rsqrtf(var + 1e-5f);
    #pragma unroll
    for (int i = 0; i < 6; i++){
      const int d = i*64 + lane;
      const float yn = (yv[i]-mu)*rs*ldin(gP, d, bf) + ldin(bP, d, bf);
      const float zg = z[(b*LL+l)*DI + d];
      ygs[j][d] = yn * zg * sigm(zg);
    }
  }
  __syncthreads();
  if (t < DM){
    const int o = t;
    float acc[8];
    #pragma unroll
    for (int j=0;j<8;j++) acc[j] = 0.f;
    for (int c = 0; c < 96; c++){
      const float4 w4 = ldin4(woP, o*DI + c*4, bf);
      #pragma unroll
      for (int j=0;j<8;j++){
        const float4 y4 = *(const float4*)&ygs[j][c*4];
        acc[j] = fmaf(w4.x, y4.x, acc[j]);
        acc[j] = fmaf(w4.y, y4.y, acc[j]);
        acc[j] = fmaf(w4.z, y4.z, acc[j]);
        acc[j] = fmaf(w4.w, y4.w, acc[j]);
      }
    }
    #pragma unroll
    for (int j=0;j<8;j++){
      const int pos = blk*8 + j;
      if (bf) ((__hip_bfloat16*)out)[pos*DM + o] = __float2bfloat16(acc[j]);
      else    ((float*)out)[pos*DM + o] = acc[j];
    }
  }
}

extern "C" void kernel_launch(void* const* d_in, const int* in_sizes, int n_in,
                              void* d_out, int out_size, void* d_ws, size_t ws_size,
                              hipStream_t stream){
  const void* x    = d_in[0];
  const void* xcr  = d_in[1];
  const void* wi   = d_in[2];
  const void* wc   = d_in[3];
  const void* cw   = d_in[4];
  const void* cb   = d_in[5];
  const void* xpw  = d_in[6];
  const void* dtw  = d_in[7];
  const void* dtb  = d_in[8];
  const void* alog = d_in[9];
  const void* dsv  = d_in[10];
  const void* gno  = d_in[11];
  const void* bno  = d_in[12];
  const void* wo   = d_in[13];

  float* ws = (float*)d_ws;
  int*   flag = (int*)ws;
  float* xp    = ws + 16;
  float* z     = xp    + (size_t)BB*LL*DI;
  float* xc    = z     + (size_t)BB*LL*DI;
  float* xh    = xc    + (size_t)BB*LL*DI;
  float* delta = xh    + (size_t)BB*LL*DI;
  float* Bm    = delta + (size_t)BB*KK*LL*DI;
  float* Cm    = Bm    + (size_t)BB*KK*LL*NS;
  float* Acum  = Cm    + (size_t)BB*KK*LL*NS;
  float* Hend  = Acum  + (size_t)GB*NC;
  float* ybuf  = Hend  + (size_t)GB*NC;

  k_detect<<<1, 1, 0, stream>>>((const unsigned*)dsv, flag);
  k_inproj<<<3*128, 192, 0, stream>>>(x, xcr, wi, wc, flag, xp, z, xc);
  k_conv  <<<BB*LL*DI/256, 256, 0, stream>>>(xp, cw, cb, flag, xh);
  k_xproj <<<BB*KK*64, 256, 0, stream>>>(xc, xpw, dtw, dtb, flag, delta, Bm, Cm);
  k_scanA <<<NCH*NC/256, 256, 0, stream>>>(delta, xh, Bm, alog, flag, Acum, Hend);
  k_scanB <<<GB/256, 256, 0, stream>>>(Acum, Hend);
  k_scanC <<<NCH*NC/256, 256, 0, stream>>>(delta, xh, Bm, Cm, alog, flag, Hend, ybuf);
  k_merge <<<BB*LL/8, 256, 0, stream>>>(ybuf, xh, z, dsv, gno, bno, wo, flag, d_out);
}

// Round 5
// 256.387 us; speedup vs baseline: 5.1610x; 1.0205x over previous
//
#include <hip/hip_runtime.h>
#include <hip/hip_bf16.h>
#include <math.h>

#define BB 2
#define HH 32
#define WW 32
#define LL 1024
#define DM 192
#define DI 384
#define NS 16
#define RR 12
#define KK 4
#define CC 44    /* RR + 2*NS */
#define NC 64    /* scan chunks */
#define LC 16    /* chunk length */
#define NCH 3072 /* B*K*DI chains */
#define GB 49152 /* NCH * NS */
#define XT 8     /* xproj positions per block */

// ---- dtype-flex loads (flag: 0=fp32, 1=bf16), decided on-device from Ds[0] ----
__device__ __forceinline__ float ldin(const void* p, int i, int bf) {
  if (bf) {
    unsigned v = ((const unsigned short*)p)[i];
    return __uint_as_float(v << 16);
  }
  return ((const float*)p)[i];
}
// 4-wide flex load; i must be a multiple of 4
__device__ __forceinline__ float4 ldin4(const void* p, int i, int bf) {
  if (bf) {
    ushort4 u = ((const ushort4*)p)[i >> 2];
    float4 r;
    r.x = __uint_as_float((unsigned)u.x << 16);
    r.y = __uint_as_float((unsigned)u.y << 16);
    r.z = __uint_as_float((unsigned)u.z << 16);
    r.w = __uint_as_float((unsigned)u.w << 16);
    return r;
  }
  return ((const float4*)p)[i >> 2];
}
__device__ __forceinline__ float sigm(float x){ return 1.f/(1.f + __expf(-x)); }
__device__ __forceinline__ float softplusf(float x){ return (x > 20.f) ? x : log1pf(__expf(x)); }

// scan-index -> physical (row-major h*W+w) index for direction k
__device__ __forceinline__ int permk(int k, int l){
  if (k == 0) return l;
  if (k == 2) return LL-1-l;
  int lr = (k == 3) ? (LL-1-l) : l;
  return (lr & 31)*WW + (lr >> 5);   // (l%H)*W + (l/H)
}

__global__ void k_detect(const unsigned* ds, int* flag){
  *flag = (*ds == 0x3F800000u) ? 0 : 1;   // fp32 ones vs bf16 pair 0x3F803F80
}

// in-projections: 16 positions per block, 1 output row per thread.
// 6 row-groups (xp lo/hi, z lo/hi, xc lo/hi) x 128 tiles = 768 blocks (9 waves/CU).
__global__ __launch_bounds__(192) void k_inproj(const void* x, const void* xcr,
    const void* wi, const void* wc, const int* flagp,
    float* __restrict__ xp, float* __restrict__ z, float* __restrict__ xc){
  const int bf = *flagp;
  __shared__ float xs_[16][DM];
  const int t = threadIdx.x;
  const int rg = blockIdx.x / 128;           // 0..5
  const int pos0 = (blockIdx.x % 128) * 16;
  const void* src = (rg >= 4) ? xcr : x;
  for (int i = t*4; i < 16*DM; i += 192*4) {
    *(float4*)&(((float*)xs_)[i]) = ldin4(src, pos0*DM + i, bf);
  }
  __syncthreads();
  const int grow = rg*192 + t;               // 0..1151
  const void* wb = (grow < 768) ? wi : wc;
  const int wrow = (grow < 768) ? grow : grow - 768;
  float* dst; int o;
  if (grow < 384)      { dst = xp; o = grow; }
  else if (grow < 768) { dst = z;  o = grow - 384; }
  else                 { dst = xc; o = grow - 768; }
  float acc[16];
  #pragma unroll
  for (int p=0;p<16;p++) acc[p]=0.f;
  for (int j=0;j<DM;j+=4) {
    const float4 w4 = ldin4(wb, wrow*DM + j, bf);
    #pragma unroll
    for (int p=0;p<16;p++){
      const float4 xv = *(const float4*)&xs_[p][j];
      acc[p] = fmaf(w4.x, xv.x, acc[p]);
      acc[p] = fmaf(w4.y, xv.y, acc[p]);
      acc[p] = fmaf(w4.z, xv.z, acc[p]);
      acc[p] = fmaf(w4.w, xv.w, acc[p]);
    }
  }
  #pragma unroll
  for (int p=0;p<16;p++) dst[(pos0+p)*DI + o] = acc[p];
}

// depthwise 3x3 conv + bias + SiLU; layout [b, l(=h*W+w), d]
__global__ __launch_bounds__(256) void k_conv(const float* __restrict__ xp,
    const void* cw, const void* cb, const int* flagp, float* __restrict__ xh){
  const int bf = *flagp;
  const int idx = blockIdx.x*256 + threadIdx.x;    // B*L*DI = 786432 exact
  const int d = idx % DI;
  const int l = (idx / DI) % LL;
  const int b = idx / (DI*LL);
  const int h = l >> 5, w = l & 31;
  float acc = ldin(cb, d, bf);
  #pragma unroll
  for (int kh=0; kh<3; kh++){
    const int hh = h + kh - 1;
    if (hh < 0 || hh >= HH) continue;
    #pragma unroll
    for (int kw=0; kw<3; kw++){
      const int ww2 = w + kw - 1;
      if (ww2 < 0 || ww2 >= WW) continue;
      acc = fmaf(xp[(b*LL + hh*WW + ww2)*DI + d], ldin(cw, d*9 + kh*3 + kw, bf), acc);
    }
  }
  xh[idx] = acc * sigm(acc);
}

// x_proj + dt_proj for 8 positions per block. grid = B*K*128 = 1024 blocks.
// dt weights live in registers (no dtwS); delta round-trips through the dead
// xrow tile for coalesced stores. LDS ~12.8 KB.
__global__ __launch_bounds__(256) void k_xproj(const float* __restrict__ xc, const void* xpw,
    const void* dtw, const void* dtb, const int* flagp,
    float* __restrict__ delta, float* __restrict__ Bm, float* __restrict__ Cm){
  const int bf = *flagp;
  const int blk = blockIdx.x;          // 1024
  const int b = blk >> 9;
  const int k = (blk >> 7) & 3;
  const int l0 = (blk & 127) * XT;
  const int t = threadIdx.x;
  __shared__ float xrow[XT][DI+4];     // pad: row stride 388 == 4 mod 32
  __shared__ float dtsS[XT][RR];
  // stage the permuted activation rows
  for (int idx = t; idx < XT*96; idx += 256){
    const int j = idx / 96, c = idx % 96;
    const int pl = permk(k, l0 + j);
    *(float4*)&xrow[j][c*4] = *(const float4*)&xc[(b*LL + pl)*DI + c*4];
  }
  __syncthreads();
  // x_dbl: 44 channels x 8 positions
  for (int idx = t; idx < CC*XT; idx += 256){
    const int ch = idx >> 3, j = idx & 7;
    float acc = 0.f;
    const int wbase = (k*CC + ch)*DI;
    for (int c = 0; c < 96; c++){
      const float4 wv = ldin4(xpw, wbase + c*4, bf);
      const float4 xv = *(const float4*)&xrow[j][c*4];
      acc = fmaf(wv.x, xv.x, acc);
      acc = fmaf(wv.y, xv.y, acc);
      acc = fmaf(wv.z, xv.z, acc);
      acc = fmaf(wv.w, xv.w, acc);
    }
    if (ch < RR)           dtsS[j][ch] = acc;
    else if (ch < RR+NS)   Bm[((b*KK+k)*LL + l0+j)*NS + (ch-RR)]    = acc;
    else                   Cm[((b*KK+k)*LL + l0+j)*NS + (ch-RR-NS)] = acc;
  }
  __syncthreads();
  // dt_proj + softplus: thread-per-d, weights in registers; dtsS reads broadcast.
  // xrow reads are all complete (pre-barrier), so overwriting it here is safe.
  for (int d = t; d < DI; d += 256){
    float w[RR];
    #pragma unroll
    for (int q = 0; q < 3; q++){
      const float4 w4 = ldin4(dtw, (k*DI+d)*RR + q*4, bf);
      w[q*4+0]=w4.x; w[q*4+1]=w4.y; w[q*4+2]=w4.z; w[q*4+3]=w4.w;
    }
    const float bias = ldin(dtb, k*DI + d, bf);
    #pragma unroll
    for (int j = 0; j < XT; j++){
      float acc = bias;
      #pragma unroll
      for (int r = 0; r < RR; r++) acc = fmaf(w[r], dtsS[j][r], acc);
      xrow[j][d] = softplusf(acc);
    }
  }
  __syncthreads();
  // coalesced delta store
  for (int idx = t; idx < XT*96; idx += 256){
    const int j = idx / 96, c = idx % 96;
    *(float4*)&delta[((b*KK+k)*LL + l0+j)*DI + c*4] = *(const float4*)&xrow[j][c*4];
  }
}

// ---- chunked selective scan, 3 passes; one thread owns a whole chain segment
// (all 16 states in registers). lanes cover 64 consecutive d -> coalesced. ----
__global__ __launch_bounds__(256) void k_scanA(const float* __restrict__ delta,
    const float* __restrict__ xh, const float* __restrict__ Bm,
    const void* alogs, const int* flagp,
    float* __restrict__ Acum, float* __restrict__ Hend){
  const int bf = *flagp;
  const int c = blockIdx.x / 12;              // chunk (uniform per block)
  const int chain = (blockIdx.x % 12)*256 + threadIdx.x;   // (b*K+k)*DI + d
  const int d = chain % DI;
  const int k = (chain / DI) & 3;
  const int b = chain / (DI*KK);
  float An[NS];
  #pragma unroll
  for (int q = 0; q < 4; q++){
    const float4 a4 = ldin4(alogs, (k*DI + d)*NS + q*4, bf);
    An[q*4+0] = -__expf(a4.x); An[q*4+1] = -__expf(a4.y);
    An[q*4+2] = -__expf(a4.z); An[q*4+3] = -__expf(a4.w);
  }
  float h[NS], Ac[NS];
  #pragma unroll
  for (int n = 0; n < NS; n++){ h[n] = 0.f; Ac[n] = 1.f; }
  const int lb = (b*KK+k)*LL;
  const int xbase = b*LL*DI + d;
  const int l0 = c*LC;
  #pragma unroll 4
  for (int l = l0; l < l0+LC; l++){
    const float dl = delta[(lb + l)*DI + d];
    const float u  = xh[xbase + permk(k,l)*DI];
    const float dlu = dl*u;
    const float4 B0 = *(const float4*)&Bm[(lb+l)*NS + 0];
    const float4 B1 = *(const float4*)&Bm[(lb+l)*NS + 4];
    const float4 B2 = *(const float4*)&Bm[(lb+l)*NS + 8];
    const float4 B3 = *(const float4*)&Bm[(lb+l)*NS + 12];
    const float Bv[NS] = {B0.x,B0.y,B0.z,B0.w, B1.x,B1.y,B1.z,B1.w,
                          B2.x,B2.y,B2.z,B2.w, B3.x,B3.y,B3.z,B3.w};
    #pragma unroll
    for (int n = 0; n < NS; n++){
      const float e = __expf(dl*An[n]);
      Ac[n] *= e;
      h[n] = fmaf(e, h[n], dlu*Bv[n]);
    }
  }
  const int obase = (c*NCH + chain)*NS;
  #pragma unroll
  for (int q = 0; q < 4; q++){
    *(float4*)&Acum[obase + q*4] = make_float4(Ac[q*4],Ac[q*4+1],Ac[q*4+2],Ac[q*4+3]);
    *(float4*)&Hend[obase + q*4] = make_float4(h[q*4],h[q*4+1],h[q*4+2],h[q*4+3]);
  }
}

__global__ __launch_bounds__(256) void k_scanB(const float* __restrict__ Acum,
    float* __restrict__ Hend){
  const int g = blockIdx.x*256 + threadIdx.x;   // GB = 49152 threads
  float h = 0.f;
  #pragma unroll 8
  for (int c = 0; c < NC; c++){
    const float a = Acum[c*GB + g];
    const float e = Hend[c*GB + g];
    Hend[c*GB + g] = h;                         // h_in for chunk c
    h = fmaf(a, h, e);
  }
}

__global__ __launch_bounds__(256) void k_scanC(const float* __restrict__ delta,
    const float* __restrict__ xh, const float* __restrict__ Bm,
    const float* __restrict__ Cm, const void* alogs, const int* flagp,
    const float* __restrict__ Hin, float* __restrict__ ybuf){
  const int bf = *flagp;
  const int c = blockIdx.x / 12;
  const int chain = (blockIdx.x % 12)*256 + threadIdx.x;
  const int d = chain % DI;
  const int k = (chain / DI) & 3;
  const int b = chain / (DI*KK);
  float An[NS];
  #pragma unroll
  for (int q = 0; q < 4; q++){
    const float4 a4 = ldin4(alogs, (k*DI + d)*NS + q*4, bf);
    An[q*4+0] = -__expf(a4.x); An[q*4+1] = -__expf(a4.y);
    An[q*4+2] = -__expf(a4.z); An[q*4+3] = -__expf(a4.w);
  }
  float h[NS];
  const int ibase = (c*NCH + chain)*NS;
  #pragma unroll
  for (int q = 0; q < 4; q++){
    const float4 h4 = *(const float4*)&Hin[ibase + q*4];
    h[q*4+0]=h4.x; h[q*4+1]=h4.y; h[q*4+2]=h4.z; h[q*4+3]=h4.w;
  }
  const int lb = (b*KK+k)*LL;
  const int xbase = b*LL*DI + d;
  const int l0 = c*LC;
  #pragma unroll 4
  for (int l = l0; l < l0+LC; l++){
    const float dl = delta[(lb + l)*DI + d];
    const float u  = xh[xbase + permk(k,l)*DI];
    const float dlu = dl*u;
    const float4 B0 = *(const float4*)&Bm[(lb+l)*NS + 0];
    const float4 B1 = *(const float4*)&Bm[(lb+l)*NS + 4];
    const float4 B2 = *(const float4*)&Bm[(lb+l)*NS + 8];
    const float4 B3 = *(const float4*)&Bm[(lb+l)*NS + 12];
    const float4 C0 = *(const float4*)&Cm[(lb+l)*NS + 0];
    const float4 C1 = *(const float4*)&Cm[(lb+l)*NS + 4];
    const float4 C2 = *(const float4*)&Cm[(lb+l)*NS + 8];
    const float4 C3 = *(const float4*)&Cm[(lb+l)*NS + 12];
    const float Bv[NS] = {B0.x,B0.y,B0.z,B0.w, B1.x,B1.y,B1.z,B1.w,
                          B2.x,B2.y,B2.z,B2.w, B3.x,B3.y,B3.z,B3.w};
    const float Cv[NS] = {C0.x,C0.y,C0.z,C0.w, C1.x,C1.y,C1.z,C1.w,
                          C2.x,C2.y,C2.z,C2.w, C3.x,C3.y,C3.z,C3.w};
    float y = 0.f;
    #pragma unroll
    for (int n = 0; n < NS; n++){
      const float e = __expf(dl*An[n]);
      h[n] = fmaf(e, h[n], dlu*Bv[n]);
      y = fmaf(h[n], Cv[n], y);
    }
    ybuf[(lb + l)*DI + d] = y;
  }
}

// merge + LN (wave-per-position butterfly, no barriers) + gate + out-proj
// 8 positions per block; out-proj weights amortized 8x with 8 FMA chains/thread.
__global__ __launch_bounds__(256) void k_merge(const float* __restrict__ scanY,
    const float* __restrict__ xh, const float* __restrict__ z,
    const void* dsP, const void* gP, const void* bP, const void* woP,
    const int* flagp, void* out){
  const int bf = *flagp;
  const int blk = blockIdx.x;          // 256
  const int t = threadIdx.x;
  const int wv = t >> 6, lane = t & 63;
  __shared__ float ygs[8][DI];
  #pragma unroll
  for (int rep = 0; rep < 2; rep++){
    const int j = wv*2 + rep;
    const int pos = blk*8 + j;
    const int b = pos >> 10, l = pos & 1023;
    const int lt = (l & 31)*32 + (l >> 5);
    float yv[6];
    float s = 0.f, s2 = 0.f;
    #pragma unroll
    for (int i = 0; i < 6; i++){
      const int d = i*64 + lane;
      float y = scanY[((b*KK+0)*LL + l        )*DI + d]
              + scanY[((b*KK+2)*LL + (LL-1-l ))*DI + d]
              + scanY[((b*KK+1)*LL + lt       )*DI + d]
              + scanY[((b*KK+3)*LL + (LL-1-lt))*DI + d];
      const float dsum = ldin(dsP, d, bf) + ldin(dsP, DI+d, bf)
                       + ldin(dsP, 2*DI+d, bf) + ldin(dsP, 3*DI+d, bf);
      y = fmaf(xh[(b*LL+l)*DI + d], dsum, y);
      yv[i] = y;
      s += y; s2 = fmaf(y, y, s2);
    }
    #pragma unroll
    for (int m = 1; m < 64; m <<= 1){
      s  += __shfl_xor(s,  m);
      s2 += __shfl_xor(s2, m);
    }
    const float mu = s * (1.f/DI);
    const float var = fmaxf(s2 * (1.f/DI) - mu*mu, 0.f);
    const float rs = rsqrtf(var + 1e-5f);
    #pragma unroll
    for (int i = 0; i < 6; i++){
      const int d = i*64 + lane;
      const float yn = (yv[i]-mu)*rs*ldin(gP, d, bf) + ldin(bP, d, bf);
      const float zg = z[(b*LL+l)*DI + d];
      ygs[j][d] = yn * zg * sigm(zg);
    }
  }
  __syncthreads();
  if (t < DM){
    const int o = t;
    float acc[8];
    #pragma unroll
    for (int j=0;j<8;j++) acc[j] = 0.f;
    for (int c = 0; c < 96; c++){
      const float4 w4 = ldin4(woP, o*DI + c*4, bf);
      #pragma unroll
      for (int j=0;j<8;j++){
        const float4 y4 = *(const float4*)&ygs[j][c*4];
        acc[j] = fmaf(w4.x, y4.x, acc[j]);
        acc[j] = fmaf(w4.y, y4.y, acc[j]);
        acc[j] = fmaf(w4.z, y4.z, acc[j]);
        acc[j] = fmaf(w4.w, y4.w, acc[j]);
      }
    }
    #pragma unroll
    for (int j=0;j<8;j++){
      const int pos = blk*8 + j;
      if (bf) ((__hip_bfloat16*)out)[pos*DM + o] = __float2bfloat16(acc[j]);
      else    ((float*)out)[pos*DM + o] = acc[j];
    }
  }
}

extern "C" void kernel_launch(void* const* d_in, const int* in_sizes, int n_in,
                              void* d_out, int out_size, void* d_ws, size_t ws_size,
                              hipStream_t stream){
  const void* x    = d_in[0];
  const void* xcr  = d_in[1];
  const void* wi   = d_in[2];
  const void* wc   = d_in[3];
  const void* cw   = d_in[4];
  const void* cb   = d_in[5];
  const void* xpw  = d_in[6];
  const void* dtw  = d_in[7];
  const void* dtb  = d_in[8];
  const void* alog = d_in[9];
  const void* dsv  = d_in[10];
  const void* gno  = d_in[11];
  const void* bno  = d_in[12];
  const void* wo   = d_in[13];

  float* ws = (float*)d_ws;
  int*   flag = (int*)ws;
  float* xp    = ws + 16;
  float* z     = xp    + (size_t)BB*LL*DI;
  float* xc    = z     + (size_t)BB*LL*DI;
  float* xh    = xc    + (size_t)BB*LL*DI;
  float* delta = xh    + (size_t)BB*LL*DI;
  float* Bm    = delta + (size_t)BB*KK*LL*DI;
  float* Cm    = Bm    + (size_t)BB*KK*LL*NS;
  float* Acum  = Cm    + (size_t)BB*KK*LL*NS;
  float* Hend  = Acum  + (size_t)GB*NC;
  float* ybuf  = Hend  + (size_t)GB*NC;

  k_detect<<<1, 1, 0, stream>>>((const unsigned*)dsv, flag);
  k_inproj<<<6*128, 192, 0, stream>>>(x, xcr, wi, wc, flag, xp, z, xc);
  k_conv  <<<BB*LL*DI/256, 256, 0, stream>>>(xp, cw, cb, flag, xh);
  k_xproj <<<BB*KK*(LL/XT), 256, 0, stream>>>(xc, xpw, dtw, dtb, flag, delta, Bm, Cm);
  k_scanA <<<NCH*NC/256, 256, 0, stream>>>(delta, xh, Bm, alog, flag, Acum, Hend);
  k_scanB <<<GB/256, 256, 0, stream>>>(Acum, Hend);
  k_scanC <<<NCH*NC/256, 256, 0, stream>>>(delta, xh, Bm, Cm, alog, flag, Hend, ybuf);
  k_merge <<<BB*LL/8, 256, 0, stream>>>(ybuf, xh, z, dsv, gno, bno, wo, flag, d_out);
}

// Round 6
// 242.857 us; speedup vs baseline: 5.4485x; 1.0557x over previous
//
#include <hip/hip_runtime.h>
#include <hip/hip_bf16.h>
#include <math.h>

#define BB 2
#define HH 32
#define WW 32
#define LL 1024
#define DM 192
#define DI 384
#define NS 16
#define RR 12
#define KK 4
#define CC 44    /* RR + 2*NS */
#define NC 64    /* scan chunks */
#define LC 16    /* chunk length */
#define NCH 3072 /* B*K*DI chains */
#define GB 49152 /* NCH * NS */
#define XT 8     /* xproj positions per block */

// ---- dtype-flex loads (bf: 0=fp32, 1=bf16), derived per-kernel from Ds[0] ----
__device__ __forceinline__ int bfflag(const void* dsv){
  return ((const unsigned*)dsv)[0] != 0x3F800000u;  // fp32 ones vs bf16 pair
}
__device__ __forceinline__ float ldin(const void* p, int i, int bf) {
  if (bf) {
    unsigned v = ((const unsigned short*)p)[i];
    return __uint_as_float(v << 16);
  }
  return ((const float*)p)[i];
}
// 4-wide flex load; i must be a multiple of 4
__device__ __forceinline__ float4 ldin4(const void* p, int i, int bf) {
  if (bf) {
    ushort4 u = ((const ushort4*)p)[i >> 2];
    float4 r;
    r.x = __uint_as_float((unsigned)u.x << 16);
    r.y = __uint_as_float((unsigned)u.y << 16);
    r.z = __uint_as_float((unsigned)u.z << 16);
    r.w = __uint_as_float((unsigned)u.w << 16);
    return r;
  }
  return ((const float4*)p)[i >> 2];
}
__device__ __forceinline__ float sigm(float x){ return 1.f/(1.f + __expf(-x)); }
__device__ __forceinline__ float softplusf(float x){ return (x > 20.f) ? x : log1pf(__expf(x)); }

// scan-index -> physical (row-major h*W+w) index for direction k
__device__ __forceinline__ int permk(int k, int l){
  if (k == 0) return l;
  if (k == 2) return LL-1-l;
  int lr = (k == 3) ? (LL-1-l) : l;
  return (lr & 31)*WW + (lr >> 5);   // (l%H)*W + (l/H)
}

// in-projections: 16 positions per block, 1 output row per thread.
// 6 row-groups x 128 tiles = 768 blocks.
__global__ __launch_bounds__(192) void k_inproj(const void* x, const void* xcr,
    const void* wi, const void* wc, const void* dsv,
    float* __restrict__ xp, float* __restrict__ z, float* __restrict__ xc){
  const int bf = bfflag(dsv);
  __shared__ float xs_[16][DM];
  const int t = threadIdx.x;
  const int rg = blockIdx.x / 128;           // 0..5
  const int pos0 = (blockIdx.x % 128) * 16;
  const void* src = (rg >= 4) ? xcr : x;
  for (int i = t*4; i < 16*DM; i += 192*4) {
    *(float4*)&(((float*)xs_)[i]) = ldin4(src, pos0*DM + i, bf);
  }
  __syncthreads();
  const int grow = rg*192 + t;               // 0..1151
  const void* wb = (grow < 768) ? wi : wc;
  const int wrow = (grow < 768) ? grow : grow - 768;
  float* dst; int o;
  if (grow < 384)      { dst = xp; o = grow; }
  else if (grow < 768) { dst = z;  o = grow - 384; }
  else                 { dst = xc; o = grow - 768; }
  float acc[16];
  #pragma unroll
  for (int p=0;p<16;p++) acc[p]=0.f;
  for (int j=0;j<DM;j+=4) {
    const float4 w4 = ldin4(wb, wrow*DM + j, bf);
    #pragma unroll
    for (int p=0;p<16;p++){
      const float4 xv = *(const float4*)&xs_[p][j];
      acc[p] = fmaf(w4.x, xv.x, acc[p]);
      acc[p] = fmaf(w4.y, xv.y, acc[p]);
      acc[p] = fmaf(w4.z, xv.z, acc[p]);
      acc[p] = fmaf(w4.w, xv.w, acc[p]);
    }
  }
  #pragma unroll
  for (int p=0;p<16;p++) dst[(pos0+p)*DI + o] = acc[p];
}

// depthwise 3x3 conv + bias + SiLU; layout [b, l(=h*W+w), d]
__global__ __launch_bounds__(256) void k_conv(const float* __restrict__ xp,
    const void* cw, const void* cb, const void* dsv, float* __restrict__ xh){
  const int bf = bfflag(dsv);
  const int idx = blockIdx.x*256 + threadIdx.x;    // B*L*DI = 786432 exact
  const int d = idx % DI;
  const int l = (idx / DI) % LL;
  const int b = idx / (DI*LL);
  const int h = l >> 5, w = l & 31;
  float acc = ldin(cb, d, bf);
  #pragma unroll
  for (int kh=0; kh<3; kh++){
    const int hh = h + kh - 1;
    if (hh < 0 || hh >= HH) continue;
    #pragma unroll
    for (int kw=0; kw<3; kw++){
      const int ww2 = w + kw - 1;
      if (ww2 < 0 || ww2 >= WW) continue;
      acc = fmaf(xp[(b*LL + hh*WW + ww2)*DI + d], ldin(cw, d*9 + kh*3 + kw, bf), acc);
    }
  }
  xh[idx] = acc * sigm(acc);
}

// x_proj + dt_proj, 8 positions per 384-thread block. grid = 1024 blocks.
// Phase-exact thread mapping: x_dbl = 1 item/thread (352 of 384),
// dt_proj = thread-per-d (384 = DI). 4-acc ILP in the 384-dot.
__global__ __launch_bounds__(384) void k_xproj(const float* __restrict__ xc, const void* xpw,
    const void* dtw, const void* dtb, const void* dsv,
    float* __restrict__ delta, float* __restrict__ Bm, float* __restrict__ Cm){
  const int bf = bfflag(dsv);
  const int blk = blockIdx.x;          // 1024
  const int b = blk >> 9;
  const int k = (blk >> 7) & 3;
  const int l0 = (blk & 127) * XT;
  const int t = threadIdx.x;
  __shared__ float xrow[XT][DI+4];     // pad: row stride 388
  __shared__ float dtsS[XT][RR];
  // stage the permuted activation rows (exactly 2 rounds)
  for (int idx = t; idx < XT*96; idx += 384){
    const int j = idx / 96, c = idx % 96;
    const int pl = permk(k, l0 + j);
    *(float4*)&xrow[j][c*4] = *(const float4*)&xc[(b*LL + pl)*DI + c*4];
  }
  __syncthreads();
  // x_dbl: 44 channels x 8 positions = 352 items, one per thread
  if (t < CC*XT){
    const int ch = t >> 3, j = t & 7;
    const int wbase = (k*CC + ch)*DI;
    float a0=0.f, a1=0.f, a2=0.f, a3=0.f;
    for (int c = 0; c < 96; c += 4){
      const float4 w0 = ldin4(xpw, wbase + (c+0)*4, bf);
      const float4 w1 = ldin4(xpw, wbase + (c+1)*4, bf);
      const float4 w2 = ldin4(xpw, wbase + (c+2)*4, bf);
      const float4 w3 = ldin4(xpw, wbase + (c+3)*4, bf);
      const float4 x0 = *(const float4*)&xrow[j][(c+0)*4];
      const float4 x1 = *(const float4*)&xrow[j][(c+1)*4];
      const float4 x2 = *(const float4*)&xrow[j][(c+2)*4];
      const float4 x3 = *(const float4*)&xrow[j][(c+3)*4];
      a0 = fmaf(w0.x,x0.x, fmaf(w0.y,x0.y, fmaf(w0.z,x0.z, fmaf(w0.w,x0.w, a0))));
      a1 = fmaf(w1.x,x1.x, fmaf(w1.y,x1.y, fmaf(w1.z,x1.z, fmaf(w1.w,x1.w, a1))));
      a2 = fmaf(w2.x,x2.x, fmaf(w2.y,x2.y, fmaf(w2.z,x2.z, fmaf(w2.w,x2.w, a2))));
      a3 = fmaf(w3.x,x3.x, fmaf(w3.y,x3.y, fmaf(w3.z,x3.z, fmaf(w3.w,x3.w, a3))));
    }
    const float acc = (a0+a1)+(a2+a3);
    if (ch < RR)           dtsS[j][ch] = acc;
    else if (ch < RR+NS)   Bm[((b*KK+k)*LL + l0+j)*NS + (ch-RR)]    = acc;
    else                   Cm[((b*KK+k)*LL + l0+j)*NS + (ch-RR-NS)] = acc;
  }
  __syncthreads();
  // dt_proj + softplus: d = t (384 = DI exactly); weights in registers,
  // dtsS reads are wave-uniform broadcasts. xrow is dead -> reuse for staging out.
  {
    const int d = t;
    float w[RR];
    #pragma unroll
    for (int q = 0; q < 3; q++){
      const float4 w4 = ldin4(dtw, (k*DI+d)*RR + q*4, bf);
      w[q*4+0]=w4.x; w[q*4+1]=w4.y; w[q*4+2]=w4.z; w[q*4+3]=w4.w;
    }
    const float bias = ldin(dtb, k*DI + d, bf);
    #pragma unroll
    for (int j = 0; j < XT; j++){
      float acc = bias;
      #pragma unroll
      for (int r = 0; r < RR; r++) acc = fmaf(w[r], dtsS[j][r], acc);
      xrow[j][d] = softplusf(acc);
    }
  }
  __syncthreads();
  // coalesced delta store (exactly 2 rounds)
  for (int idx = t; idx < XT*96; idx += 384){
    const int j = idx / 96, c = idx % 96;
    *(float4*)&delta[((b*KK+k)*LL + l0+j)*DI + c*4] = *(const float4*)&xrow[j][c*4];
  }
}

// ---- chunked selective scan, 3 passes; one thread owns a whole chain segment
// (all 16 states in registers). lanes cover 64 consecutive d -> coalesced. ----
__global__ __launch_bounds__(256) void k_scanA(const float* __restrict__ delta,
    const float* __restrict__ xh, const float* __restrict__ Bm,
    const void* alogs, const void* dsv,
    float* __restrict__ Acum, float* __restrict__ Hend){
  const int bf = bfflag(dsv);
  const int c = blockIdx.x / 12;              // chunk (uniform per block)
  const int chain = (blockIdx.x % 12)*256 + threadIdx.x;   // (b*K+k)*DI + d
  const int d = chain % DI;
  const int k = (chain / DI) & 3;
  const int b = chain / (DI*KK);
  float An[NS];
  #pragma unroll
  for (int q = 0; q < 4; q++){
    const float4 a4 = ldin4(alogs, (k*DI + d)*NS + q*4, bf);
    An[q*4+0] = -__expf(a4.x); An[q*4+1] = -__expf(a4.y);
    An[q*4+2] = -__expf(a4.z); An[q*4+3] = -__expf(a4.w);
  }
  float h[NS], Ac[NS];
  #pragma unroll
  for (int n = 0; n < NS; n++){ h[n] = 0.f; Ac[n] = 1.f; }
  const int lb = (b*KK+k)*LL;
  const int xbase = b*LL*DI + d;
  const int l0 = c*LC;
  #pragma unroll 4
  for (int l = l0; l < l0+LC; l++){
    const float dl = delta[(lb + l)*DI + d];
    const float u  = xh[xbase + permk(k,l)*DI];
    const float dlu = dl*u;
    const float4 B0 = *(const float4*)&Bm[(lb+l)*NS + 0];
    const float4 B1 = *(const float4*)&Bm[(lb+l)*NS + 4];
    const float4 B2 = *(const float4*)&Bm[(lb+l)*NS + 8];
    const float4 B3 = *(const float4*)&Bm[(lb+l)*NS + 12];
    const float Bv[NS] = {B0.x,B0.y,B0.z,B0.w, B1.x,B1.y,B1.z,B1.w,
                          B2.x,B2.y,B2.z,B2.w, B3.x,B3.y,B3.z,B3.w};
    #pragma unroll
    for (int n = 0; n < NS; n++){
      const float e = __expf(dl*An[n]);
      Ac[n] *= e;
      h[n] = fmaf(e, h[n], dlu*Bv[n]);
    }
  }
  const int obase = (c*NCH + chain)*NS;
  #pragma unroll
  for (int q = 0; q < 4; q++){
    *(float4*)&Acum[obase + q*4] = make_float4(Ac[q*4],Ac[q*4+1],Ac[q*4+2],Ac[q*4+3]);
    *(float4*)&Hend[obase + q*4] = make_float4(h[q*4],h[q*4+1],h[q*4+2],h[q*4+3]);
  }
}

__global__ __launch_bounds__(256) void k_scanB(const float* __restrict__ Acum,
    float* __restrict__ Hend){
  const int g = blockIdx.x*256 + threadIdx.x;   // GB = 49152 threads
  float h = 0.f;
  #pragma unroll 8
  for (int c = 0; c < NC; c++){
    const float a = Acum[c*GB + g];
    const float e = Hend[c*GB + g];
    Hend[c*GB + g] = h;                         // h_in for chunk c
    h = fmaf(a, h, e);
  }
}

__global__ __launch_bounds__(256) void k_scanC(const float* __restrict__ delta,
    const float* __restrict__ xh, const float* __restrict__ Bm,
    const float* __restrict__ Cm, const void* alogs, const void* dsv,
    const float* __restrict__ Hin, float* __restrict__ ybuf){
  const int bf = bfflag(dsv);
  const int c = blockIdx.x / 12;
  const int chain = (blockIdx.x % 12)*256 + threadIdx.x;
  const int d = chain % DI;
  const int k = (chain / DI) & 3;
  const int b = chain / (DI*KK);
  float An[NS];
  #pragma unroll
  for (int q = 0; q < 4; q++){
    const float4 a4 = ldin4(alogs, (k*DI + d)*NS + q*4, bf);
    An[q*4+0] = -__expf(a4.x); An[q*4+1] = -__expf(a4.y);
    An[q*4+2] = -__expf(a4.z); An[q*4+3] = -__expf(a4.w);
  }
  float h[NS];
  const int ibase = (c*NCH + chain)*NS;
  #pragma unroll
  for (int q = 0; q < 4; q++){
    const float4 h4 = *(const float4*)&Hin[ibase + q*4];
    h[q*4+0]=h4.x; h[q*4+1]=h4.y; h[q*4+2]=h4.z; h[q*4+3]=h4.w;
  }
  const int lb = (b*KK+k)*LL;
  const int xbase = b*LL*DI + d;
  const int l0 = c*LC;
  #pragma unroll 4
  for (int l = l0; l < l0+LC; l++){
    const float dl = delta[(lb + l)*DI + d];
    const float u  = xh[xbase + permk(k,l)*DI];
    const float dlu = dl*u;
    const float4 B0 = *(const float4*)&Bm[(lb+l)*NS + 0];
    const float4 B1 = *(const float4*)&Bm[(lb+l)*NS + 4];
    const float4 B2 = *(const float4*)&Bm[(lb+l)*NS + 8];
    const float4 B3 = *(const float4*)&Bm[(lb+l)*NS + 12];
    const float4 C0 = *(const float4*)&Cm[(lb+l)*NS + 0];
    const float4 C1 = *(const float4*)&Cm[(lb+l)*NS + 4];
    const float4 C2 = *(const float4*)&Cm[(lb+l)*NS + 8];
    const float4 C3 = *(const float4*)&Cm[(lb+l)*NS + 12];
    const float Bv[NS] = {B0.x,B0.y,B0.z,B0.w, B1.x,B1.y,B1.z,B1.w,
                          B2.x,B2.y,B2.z,B2.w, B3.x,B3.y,B3.z,B3.w};
    const float Cv[NS] = {C0.x,C0.y,C0.z,C0.w, C1.x,C1.y,C1.z,C1.w,
                          C2.x,C2.y,C2.z,C2.w, C3.x,C3.y,C3.z,C3.w};
    float y = 0.f;
    #pragma unroll
    for (int n = 0; n < NS; n++){
      const float e = __expf(dl*An[n]);
      h[n] = fmaf(e, h[n], dlu*Bv[n]);
      y = fmaf(h[n], Cv[n], y);
    }
    ybuf[(lb + l)*DI + d] = y;
  }
}

// merge + LN (wave-per-position butterfly) + gate + out-proj
// 8 positions per block; out-proj weights amortized 8x with 8 FMA chains/thread.
__global__ __launch_bounds__(256) void k_merge(const float* __restrict__ scanY,
    const float* __restrict__ xh, const float* __restrict__ z,
    const void* dsP, const void* gP, const void* bP, const void* woP,
    void* out){
  const int bf = bfflag(dsP);
  const int blk = blockIdx.x;          // 256
  const int t = threadIdx.x;
  const int wv = t >> 6, lane = t & 63;
  __shared__ float ygs[8][DI];
  #pragma unroll
  for (int rep = 0; rep < 2; rep++){
    const int j = wv*2 + rep;
    const int pos = blk*8 + j;
    const int b = pos >> 10, l = pos & 1023;
    const int lt = (l & 31)*32 + (l >> 5);
    float yv[6];
    float s = 0.f, s2 = 0.f;
    #pragma unroll
    for (int i = 0; i < 6; i++){
      const int d = i*64 + lane;
      float y = scanY[((b*KK+0)*LL + l        )*DI + d]
              + scanY[((b*KK+2)*LL + (LL-1-l ))*DI + d]
              + scanY[((b*KK+1)*LL + lt       )*DI + d]
              + scanY[((b*KK+3)*LL + (LL-1-lt))*DI + d];
      const float dsum = ldin(dsP, d, bf) + ldin(dsP, DI+d, bf)
                       + ldin(dsP, 2*DI+d, bf) + ldin(dsP, 3*DI+d, bf);
      y = fmaf(xh[(b*LL+l)*DI + d], dsum, y);
      yv[i] = y;
      s += y; s2 = fmaf(y, y, s2);
    }
    #pragma unroll
    for (int m = 1; m < 64; m <<= 1){
      s  += __shfl_xor(s,  m);
      s2 += __shfl_xor(s2, m);
    }
    const float mu = s * (1.f/DI);
    const float var = fmaxf(s2 * (1.f/DI) - mu*mu, 0.f);
    const float rs = rsqrtf(var + 1e-5f);
    #pragma unroll
    for (int i = 0; i < 6; i++){
      const int d = i*64 + lane;
      const float yn = (yv[i]-mu)*rs*ldin(gP, d, bf) + ldin(bP, d, bf);
      const float zg = z[(b*LL+l)*DI + d];
      ygs[j][d] = yn * zg * sigm(zg);
    }
  }
  __syncthreads();
  if (t < DM){
    const int o = t;
    float acc[8];
    #pragma unroll
    for (int j=0;j<8;j++) acc[j] = 0.f;
    for (int c = 0; c < 96; c++){
      const float4 w4 = ldin4(woP, o*DI + c*4, bf);
      #pragma unroll
      for (int j=0;j<8;j++){
        const float4 y4 = *(const float4*)&ygs[j][c*4];
        acc[j] = fmaf(w4.x, y4.x, acc[j]);
        acc[j] = fmaf(w4.y, y4.y, acc[j]);
        acc[j] = fmaf(w4.z, y4.z, acc[j]);
        acc[j] = fmaf(w4.w, y4.w, acc[j]);
      }
    }
    #pragma unroll
    for (int j=0;j<8;j++){
      const int pos = blk*8 + j;
      if (bf) ((__hip_bfloat16*)out)[pos*DM + o] = __float2bfloat16(acc[j]);
      else    ((float*)out)[pos*DM + o] = acc[j];
    }
  }
}

extern "C" void kernel_launch(void* const* d_in, const int* in_sizes, int n_in,
                              void* d_out, int out_size, void* d_ws, size_t ws_size,
                              hipStream_t stream){
  const void* x    = d_in[0];
  const void* xcr  = d_in[1];
  const void* wi   = d_in[2];
  const void* wc   = d_in[3];
  const void* cw   = d_in[4];
  const void* cb   = d_in[5];
  const void* xpw  = d_in[6];
  const void* dtw  = d_in[7];
  const void* dtb  = d_in[8];
  const void* alog = d_in[9];
  const void* dsv  = d_in[10];
  const void* gno  = d_in[11];
  const void* bno  = d_in[12];
  const void* wo   = d_in[13];

  float* ws = (float*)d_ws;
  float* xp    = ws + 16;
  float* z     = xp    + (size_t)BB*LL*DI;
  float* xc    = z     + (size_t)BB*LL*DI;
  float* xh    = xc    + (size_t)BB*LL*DI;
  float* delta = xh    + (size_t)BB*LL*DI;
  float* Bm    = delta + (size_t)BB*KK*LL*DI;
  float* Cm    = Bm    + (size_t)BB*KK*LL*NS;
  float* Acum  = Cm    + (size_t)BB*KK*LL*NS;
  float* Hend  = Acum  + (size_t)GB*NC;
  float* ybuf  = Hend  + (size_t)GB*NC;

  k_inproj<<<6*128, 192, 0, stream>>>(x, xcr, wi, wc, dsv, xp, z, xc);
  k_conv  <<<BB*LL*DI/256, 256, 0, stream>>>(xp, cw, cb, dsv, xh);
  k_xproj <<<BB*KK*(LL/XT), 384, 0, stream>>>(xc, xpw, dtw, dtb, dsv, delta, Bm, Cm);
  k_scanA <<<NCH*NC/256, 256, 0, stream>>>(delta, xh, Bm, alog, dsv, Acum, Hend);
  k_scanB <<<GB/256, 256, 0, stream>>>(Acum, Hend);
  k_scanC <<<NCH*NC/256, 256, 0, stream>>>(delta, xh, Bm, Cm, alog, dsv, Hend, ybuf);
  k_merge <<<BB*LL/8, 256, 0, stream>>>(ybuf, xh, z, dsv, gno, bno, wo, d_out);
}

// Round 7
// 239.223 us; speedup vs baseline: 5.5313x; 1.0152x over previous
//
#include <hip/hip_runtime.h>
#include <hip/hip_bf16.h>
#include <math.h>

#define BB 2
#define HH 32
#define WW 32
#define LL 1024
#define DM 192
#define DI 384
#define NS 16
#define RR 12
#define KK 4
#define CC 44    /* RR + 2*NS */
#define NC 64    /* scan chunks */
#define LC 16    /* chunk length */
#define NCH 3072 /* B*K*DI chains */
#define GB 49152 /* NCH * NS */
#define XT 8     /* xproj positions per block */

typedef __bf16 bf16x8 __attribute__((ext_vector_type(8)));
typedef float  f32x4  __attribute__((ext_vector_type(4)));

// ---- dtype-flex loads (bf: 0=fp32, 1=bf16), derived per-kernel from Ds[0] ----
__device__ __forceinline__ int bfflag(const void* dsv){
  return ((const unsigned*)dsv)[0] != 0x3F800000u;  // fp32 ones vs bf16 pair
}
__device__ __forceinline__ float ldin(const void* p, int i, int bf) {
  if (bf) {
    unsigned v = ((const unsigned short*)p)[i];
    return __uint_as_float(v << 16);
  }
  return ((const float*)p)[i];
}
// 4-wide flex load; i must be a multiple of 4
__device__ __forceinline__ float4 ldin4(const void* p, int i, int bf) {
  if (bf) {
    ushort4 u = ((const ushort4*)p)[i >> 2];
    float4 r;
    r.x = __uint_as_float((unsigned)u.x << 16);
    r.y = __uint_as_float((unsigned)u.y << 16);
    r.z = __uint_as_float((unsigned)u.z << 16);
    r.w = __uint_as_float((unsigned)u.w << 16);
    return r;
  }
  return ((const float4*)p)[i >> 2];
}
__device__ __forceinline__ float sigm(float x){ return 1.f/(1.f + __expf(-x)); }
__device__ __forceinline__ float softplusf(float x){ return (x > 20.f) ? x : log1pf(__expf(x)); }

// scan-index -> physical (row-major h*W+w) index for direction k
__device__ __forceinline__ int permk(int k, int l){
  if (k == 0) return l;
  if (k == 2) return LL-1-l;
  int lr = (k == 3) ? (LL-1-l) : l;
  return (lr & 31)*WW + (lr >> 5);   // (l%H)*W + (l/H)
}

// ---- MFMA in-projection (bf16 inputs only) ----
// C[2048 x 1152] = [x|xcr][2048 x 192] . [wi|wc]^T. Block: 64 pos x 128 rows,
// 4 waves; wave = 4 m-tiles x 2 n-tiles of 16x16, K=192 -> 6 mfma steps.
__global__ __launch_bounds__(256) void k_inproj_mfma(const void* x, const void* xcr,
    const void* wi, const void* wc, const void* dsv,
    float* __restrict__ xp, float* __restrict__ z, float* __restrict__ xcd){
  if (!bfflag(dsv)) return;
  __shared__ unsigned short xs[64*200];      // A-tile, row stride 200 bf16 (400 B)
  const int t = threadIdx.x;
  const int mb = blockIdx.x & 31;            // 32 M-blocks
  const int nb = blockIdx.x >> 5;            // 9 N-blocks (6 -> wi, 3 -> wc)
  const int pos0 = mb*64;
  const unsigned short* src  = (const unsigned short*)((nb < 6) ? x  : xcr);
  const unsigned short* wsrc = (const unsigned short*)((nb < 6) ? wi : wc);
  const int row0 = (nb < 6) ? nb*128 : (nb-6)*128;   // row within wsrc
  const int gbase = (nb < 6) ? 0 : 768;              // global output row base
  // stage A-tile: 64 pos x 192 k (uint4 = 8 bf16 per load)
  for (int i = t; i < 768; i += 256){
    const int p = i / 12, c = i % 12;
    *(uint4*)(xs + p*200 + c*8) = *(const uint4*)(src + (size_t)(pos0+p)*DM + c*8);
  }
  __syncthreads();
  const int wv = t >> 6, lane = t & 63;
  const int lo16 = lane & 15, quad = lane >> 4;
  const int nrow = row0 + wv*32;             // wave's first weight row
  f32x4 acc[4][2];
  #pragma unroll
  for (int m=0;m<4;m++){
    #pragma unroll
    for (int n=0;n<2;n++) acc[m][n] = (f32x4){0.f,0.f,0.f,0.f};
  }
  #pragma unroll
  for (int ks = 0; ks < 6; ks++){
    const int kb = ks*32;
    bf16x8 a[4], bf_[2];
    #pragma unroll
    for (int m=0;m<4;m++)
      a[m] = *(const bf16x8*)(xs + (m*16 + lo16)*200 + kb + quad*8);
    #pragma unroll
    for (int n=0;n<2;n++)
      bf_[n] = *(const bf16x8*)(wsrc + (size_t)(nrow + n*16 + lo16)*DM + kb + quad*8);
    #pragma unroll
    for (int m=0;m<4;m++){
      #pragma unroll
      for (int n=0;n<2;n++)
        acc[m][n] = __builtin_amdgcn_mfma_f32_16x16x32_bf16(a[m], bf_[n], acc[m][n], 0,0,0);
    }
  }
  // C/D: m = quad*4 + reg (pos offset), n = lane&15 (weight-row offset)
  #pragma unroll
  for (int n=0;n<2;n++){
    const int grow = gbase + nrow + n*16 + lo16;
    float* dst; int o;
    if (grow < 384)      { dst = xp;  o = grow; }
    else if (grow < 768) { dst = z;   o = grow-384; }
    else                 { dst = xcd; o = grow-768; }
    #pragma unroll
    for (int m=0;m<4;m++){
      #pragma unroll
      for (int r=0;r<4;r++){
        const int pos = pos0 + m*16 + quad*4 + r;
        dst[(size_t)pos*DI + o] = acc[m][n][r];
      }
    }
  }
}

// fp32-input fallback (dead when inputs are bf16): previous VALU version.
__global__ __launch_bounds__(192) void k_inproj_valu(const void* x, const void* xcr,
    const void* wi, const void* wc, const void* dsv,
    float* __restrict__ xp, float* __restrict__ z, float* __restrict__ xc){
  const int bf = bfflag(dsv);
  if (bf) return;
  __shared__ float xs_[16][DM];
  const int t = threadIdx.x;
  const int rg = blockIdx.x / 128;           // 0..5
  const int pos0 = (blockIdx.x % 128) * 16;
  const void* src = (rg >= 4) ? xcr : x;
  for (int i = t*4; i < 16*DM; i += 192*4) {
    *(float4*)&(((float*)xs_)[i]) = ldin4(src, pos0*DM + i, bf);
  }
  __syncthreads();
  const int grow = rg*192 + t;               // 0..1151
  const void* wb = (grow < 768) ? wi : wc;
  const int wrow = (grow < 768) ? grow : grow - 768;
  float* dst; int o;
  if (grow < 384)      { dst = xp; o = grow; }
  else if (grow < 768) { dst = z;  o = grow - 384; }
  else                 { dst = xc; o = grow - 768; }
  float acc[16];
  #pragma unroll
  for (int p=0;p<16;p++) acc[p]=0.f;
  for (int j=0;j<DM;j+=4) {
    const float4 w4 = ldin4(wb, wrow*DM + j, bf);
    #pragma unroll
    for (int p=0;p<16;p++){
      const float4 xv = *(const float4*)&xs_[p][j];
      acc[p] = fmaf(w4.x, xv.x, acc[p]);
      acc[p] = fmaf(w4.y, xv.y, acc[p]);
      acc[p] = fmaf(w4.z, xv.z, acc[p]);
      acc[p] = fmaf(w4.w, xv.w, acc[p]);
    }
  }
  #pragma unroll
  for (int p=0;p<16;p++) dst[(pos0+p)*DI + o] = acc[p];
}

// depthwise 3x3 conv + bias + SiLU; layout [b, l(=h*W+w), d]
__global__ __launch_bounds__(256) void k_conv(const float* __restrict__ xp,
    const void* cw, const void* cb, const void* dsv, float* __restrict__ xh){
  const int bf = bfflag(dsv);
  const int idx = blockIdx.x*256 + threadIdx.x;    // B*L*DI = 786432 exact
  const int d = idx % DI;
  const int l = (idx / DI) % LL;
  const int b = idx / (DI*LL);
  const int h = l >> 5, w = l & 31;
  float acc = ldin(cb, d, bf);
  #pragma unroll
  for (int kh=0; kh<3; kh++){
    const int hh = h + kh - 1;
    if (hh < 0 || hh >= HH) continue;
    #pragma unroll
    for (int kw=0; kw<3; kw++){
      const int ww2 = w + kw - 1;
      if (ww2 < 0 || ww2 >= WW) continue;
      acc = fmaf(xp[(b*LL + hh*WW + ww2)*DI + d], ldin(cw, d*9 + kh*3 + kw, bf), acc);
    }
  }
  xh[idx] = acc * sigm(acc);
}

// x_proj + dt_proj, 8 positions per 384-thread block. grid = 1024 blocks.
__global__ __launch_bounds__(384) void k_xproj(const float* __restrict__ xc, const void* xpw,
    const void* dtw, const void* dtb, const void* dsv,
    float* __restrict__ delta, float* __restrict__ Bm, float* __restrict__ Cm){
  const int bf = bfflag(dsv);
  const int blk = blockIdx.x;          // 1024
  const int b = blk >> 9;
  const int k = (blk >> 7) & 3;
  const int l0 = (blk & 127) * XT;
  const int t = threadIdx.x;
  __shared__ float xrow[XT][DI+4];     // pad: row stride 388
  __shared__ float dtsS[XT][RR];
  for (int idx = t; idx < XT*96; idx += 384){
    const int j = idx / 96, c = idx % 96;
    const int pl = permk(k, l0 + j);
    *(float4*)&xrow[j][c*4] = *(const float4*)&xc[(b*LL + pl)*DI + c*4];
  }
  __syncthreads();
  if (t < CC*XT){
    const int ch = t >> 3, j = t & 7;
    const int wbase = (k*CC + ch)*DI;
    float a0=0.f, a1=0.f, a2=0.f, a3=0.f;
    for (int c = 0; c < 96; c += 4){
      const float4 w0 = ldin4(xpw, wbase + (c+0)*4, bf);
      const float4 w1 = ldin4(xpw, wbase + (c+1)*4, bf);
      const float4 w2 = ldin4(xpw, wbase + (c+2)*4, bf);
      const float4 w3 = ldin4(xpw, wbase + (c+3)*4, bf);
      const float4 x0 = *(const float4*)&xrow[j][(c+0)*4];
      const float4 x1 = *(const float4*)&xrow[j][(c+1)*4];
      const float4 x2 = *(const float4*)&xrow[j][(c+2)*4];
      const float4 x3 = *(const float4*)&xrow[j][(c+3)*4];
      a0 = fmaf(w0.x,x0.x, fmaf(w0.y,x0.y, fmaf(w0.z,x0.z, fmaf(w0.w,x0.w, a0))));
      a1 = fmaf(w1.x,x1.x, fmaf(w1.y,x1.y, fmaf(w1.z,x1.z, fmaf(w1.w,x1.w, a1))));
      a2 = fmaf(w2.x,x2.x, fmaf(w2.y,x2.y, fmaf(w2.z,x2.z, fmaf(w2.w,x2.w, a2))));
      a3 = fmaf(w3.x,x3.x, fmaf(w3.y,x3.y, fmaf(w3.z,x3.z, fmaf(w3.w,x3.w, a3))));
    }
    const float acc = (a0+a1)+(a2+a3);
    if (ch < RR)           dtsS[j][ch] = acc;
    else if (ch < RR+NS)   Bm[((b*KK+k)*LL + l0+j)*NS + (ch-RR)]    = acc;
    else                   Cm[((b*KK+k)*LL + l0+j)*NS + (ch-RR-NS)] = acc;
  }
  __syncthreads();
  {
    const int d = t;
    float w[RR];
    #pragma unroll
    for (int q = 0; q < 3; q++){
      const float4 w4 = ldin4(dtw, (k*DI+d)*RR + q*4, bf);
      w[q*4+0]=w4.x; w[q*4+1]=w4.y; w[q*4+2]=w4.z; w[q*4+3]=w4.w;
    }
    const float bias = ldin(dtb, k*DI + d, bf);
    #pragma unroll
    for (int j = 0; j < XT; j++){
      float acc = bias;
      #pragma unroll
      for (int r = 0; r < RR; r++) acc = fmaf(w[r], dtsS[j][r], acc);
      xrow[j][d] = softplusf(acc);
    }
  }
  __syncthreads();
  for (int idx = t; idx < XT*96; idx += 384){
    const int j = idx / 96, c = idx % 96;
    *(float4*)&delta[((b*KK+k)*LL + l0+j)*DI + c*4] = *(const float4*)&xrow[j][c*4];
  }
}

// ---- chunked selective scan, 3 passes ----
__global__ __launch_bounds__(256) void k_scanA(const float* __restrict__ delta,
    const float* __restrict__ xh, const float* __restrict__ Bm,
    const void* alogs, const void* dsv,
    float* __restrict__ Acum, float* __restrict__ Hend){
  const int bf = bfflag(dsv);
  const int c = blockIdx.x / 12;              // chunk (uniform per block)
  const int chain = (blockIdx.x % 12)*256 + threadIdx.x;   // (b*K+k)*DI + d
  const int d = chain % DI;
  const int k = (chain / DI) & 3;
  const int b = chain / (DI*KK);
  float An[NS];
  #pragma unroll
  for (int q = 0; q < 4; q++){
    const float4 a4 = ldin4(alogs, (k*DI + d)*NS + q*4, bf);
    An[q*4+0] = -__expf(a4.x); An[q*4+1] = -__expf(a4.y);
    An[q*4+2] = -__expf(a4.z); An[q*4+3] = -__expf(a4.w);
  }
  float h[NS], Ac[NS];
  #pragma unroll
  for (int n = 0; n < NS; n++){ h[n] = 0.f; Ac[n] = 1.f; }
  const int lb = (b*KK+k)*LL;
  const int xbase = b*LL*DI + d;
  const int l0 = c*LC;
  #pragma unroll 4
  for (int l = l0; l < l0+LC; l++){
    const float dl = delta[(lb + l)*DI + d];
    const float u  = xh[xbase + permk(k,l)*DI];
    const float dlu = dl*u;
    const float4 B0 = *(const float4*)&Bm[(lb+l)*NS + 0];
    const float4 B1 = *(const float4*)&Bm[(lb+l)*NS + 4];
    const float4 B2 = *(const float4*)&Bm[(lb+l)*NS + 8];
    const float4 B3 = *(const float4*)&Bm[(lb+l)*NS + 12];
    const float Bv[NS] = {B0.x,B0.y,B0.z,B0.w, B1.x,B1.y,B1.z,B1.w,
                          B2.x,B2.y,B2.z,B2.w, B3.x,B3.y,B3.z,B3.w};
    #pragma unroll
    for (int n = 0; n < NS; n++){
      const float e = __expf(dl*An[n]);
      Ac[n] *= e;
      h[n] = fmaf(e, h[n], dlu*Bv[n]);
    }
  }
  const int obase = (c*NCH + chain)*NS;
  #pragma unroll
  for (int q = 0; q < 4; q++){
    *(float4*)&Acum[obase + q*4] = make_float4(Ac[q*4],Ac[q*4+1],Ac[q*4+2],Ac[q*4+3]);
    *(float4*)&Hend[obase + q*4] = make_float4(h[q*4],h[q*4+1],h[q*4+2],h[q*4+3]);
  }
}

__global__ __launch_bounds__(256) void k_scanB(const float* __restrict__ Acum,
    float* __restrict__ Hend){
  const int g = blockIdx.x*256 + threadIdx.x;   // GB = 49152 threads
  float h = 0.f;
  #pragma unroll 8
  for (int c = 0; c < NC; c++){
    const float a = Acum[c*GB + g];
    const float e = Hend[c*GB + g];
    Hend[c*GB + g] = h;                         // h_in for chunk c
    h = fmaf(a, h, e);
  }
}

__global__ __launch_bounds__(256) void k_scanC(const float* __restrict__ delta,
    const float* __restrict__ xh, const float* __restrict__ Bm,
    const float* __restrict__ Cm, const void* alogs, const void* dsv,
    const float* __restrict__ Hin, float* __restrict__ ybuf){
  const int bf = bfflag(dsv);
  const int c = blockIdx.x / 12;
  const int chain = (blockIdx.x % 12)*256 + threadIdx.x;
  const int d = chain % DI;
  const int k = (chain / DI) & 3;
  const int b = chain / (DI*KK);
  float An[NS];
  #pragma unroll
  for (int q = 0; q < 4; q++){
    const float4 a4 = ldin4(alogs, (k*DI + d)*NS + q*4, bf);
    An[q*4+0] = -__expf(a4.x); An[q*4+1] = -__expf(a4.y);
    An[q*4+2] = -__expf(a4.z); An[q*4+3] = -__expf(a4.w);
  }
  float h[NS];
  const int ibase = (c*NCH + chain)*NS;
  #pragma unroll
  for (int q = 0; q < 4; q++){
    const float4 h4 = *(const float4*)&Hin[ibase + q*4];
    h[q*4+0]=h4.x; h[q*4+1]=h4.y; h[q*4+2]=h4.z; h[q*4+3]=h4.w;
  }
  const int lb = (b*KK+k)*LL;
  const int xbase = b*LL*DI + d;
  const int l0 = c*LC;
  #pragma unroll 4
  for (int l = l0; l < l0+LC; l++){
    const float dl = delta[(lb + l)*DI + d];
    const float u  = xh[xbase + permk(k,l)*DI];
    const float dlu = dl*u;
    const float4 B0 = *(const float4*)&Bm[(lb+l)*NS + 0];
    const float4 B1 = *(const float4*)&Bm[(lb+l)*NS + 4];
    const float4 B2 = *(const float4*)&Bm[(lb+l)*NS + 8];
    const float4 B3 = *(const float4*)&Bm[(lb+l)*NS + 12];
    const float4 C0 = *(const float4*)&Cm[(lb+l)*NS + 0];
    const float4 C1 = *(const float4*)&Cm[(lb+l)*NS + 4];
    const float4 C2 = *(const float4*)&Cm[(lb+l)*NS + 8];
    const float4 C3 = *(const float4*)&Cm[(lb+l)*NS + 12];
    const float Bv[NS] = {B0.x,B0.y,B0.z,B0.w, B1.x,B1.y,B1.z,B1.w,
                          B2.x,B2.y,B2.z,B2.w, B3.x,B3.y,B3.z,B3.w};
    const float Cv[NS] = {C0.x,C0.y,C0.z,C0.w, C1.x,C1.y,C1.z,C1.w,
                          C2.x,C2.y,C2.z,C2.w, C3.x,C3.y,C3.z,C3.w};
    float y = 0.f;
    #pragma unroll
    for (int n = 0; n < NS; n++){
      const float e = __expf(dl*An[n]);
      h[n] = fmaf(e, h[n], dlu*Bv[n]);
      y = fmaf(h[n], Cv[n], y);
    }
    ybuf[(lb + l)*DI + d] = y;
  }
}

// merge + LN (wave-per-position butterfly) + gate + out-proj
__global__ __launch_bounds__(256) void k_merge(const float* __restrict__ scanY,
    const float* __restrict__ xh, const float* __restrict__ z,
    const void* dsP, const void* gP, const void* bP, const void* woP,
    void* out){
  const int bf = bfflag(dsP);
  const int blk = blockIdx.x;          // 256
  const int t = threadIdx.x;
  const int wv = t >> 6, lane = t & 63;
  __shared__ float ygs[8][DI];
  #pragma unroll
  for (int rep = 0; rep < 2; rep++){
    const int j = wv*2 + rep;
    const int pos = blk*8 + j;
    const int b = pos >> 10, l = pos & 1023;
    const int lt = (l & 31)*32 + (l >> 5);
    float yv[6];
    float s = 0.f, s2 = 0.f;
    #pragma unroll
    for (int i = 0; i < 6; i++){
      const int d = i*64 + lane;
      float y = scanY[((b*KK+0)*LL + l        )*DI + d]
              + scanY[((b*KK+2)*LL + (LL-1-l ))*DI + d]
              + scanY[((b*KK+1)*LL + lt       )*DI + d]
              + scanY[((b*KK+3)*LL + (LL-1-lt))*DI + d];
      const float dsum = ldin(dsP, d, bf) + ldin(dsP, DI+d, bf)
                       + ldin(dsP, 2*DI+d, bf) + ldin(dsP, 3*DI+d, bf);
      y = fmaf(xh[(b*LL+l)*DI + d], dsum, y);
      yv[i] = y;
      s += y; s2 = fmaf(y, y, s2);
    }
    #pragma unroll
    for (int m = 1; m < 64; m <<= 1){
      s  += __shfl_xor(s,  m);
      s2 += __shfl_xor(s2, m);
    }
    const float mu = s * (1.f/DI);
    const float var = fmaxf(s2 * (1.f/DI) - mu*mu, 0.f);
    const float rs = rsqrtf(var + 1e-5f);
    #pragma unroll
    for (int i = 0; i < 6; i++){
      const int d = i*64 + lane;
      const float yn = (yv[i]-mu)*rs*ldin(gP, d, bf) + ldin(bP, d, bf);
      const float zg = z[(b*LL+l)*DI + d];
      ygs[j][d] = yn * zg * sigm(zg);
    }
  }
  __syncthreads();
  if (t < DM){
    const int o = t;
    float acc[8];
    #pragma unroll
    for (int j=0;j<8;j++) acc[j] = 0.f;
    for (int c = 0; c < 96; c++){
      const float4 w4 = ldin4(woP, o*DI + c*4, bf);
      #pragma unroll
      for (int j=0;j<8;j++){
        const float4 y4 = *(const float4*)&ygs[j][c*4];
        acc[j] = fmaf(w4.x, y4.x, acc[j]);
        acc[j] = fmaf(w4.y, y4.y, acc[j]);
        acc[j] = fmaf(w4.z, y4.z, acc[j]);
        acc[j] = fmaf(w4.w, y4.w, acc[j]);
      }
    }
    #pragma unroll
    for (int j=0;j<8;j++){
      const int pos = blk*8 + j;
      if (bf) ((__hip_bfloat16*)out)[pos*DM + o] = __float2bfloat16(acc[j]);
      else    ((float*)out)[pos*DM + o] = acc[j];
    }
  }
}

extern "C" void kernel_launch(void* const* d_in, const int* in_sizes, int n_in,
                              void* d_out, int out_size, void* d_ws, size_t ws_size,
                              hipStream_t stream){
  const void* x    = d_in[0];
  const void* xcr  = d_in[1];
  const void* wi   = d_in[2];
  const void* wc   = d_in[3];
  const void* cw   = d_in[4];
  const void* cb   = d_in[5];
  const void* xpw  = d_in[6];
  const void* dtw  = d_in[7];
  const void* dtb  = d_in[8];
  const void* alog = d_in[9];
  const void* dsv  = d_in[10];
  const void* gno  = d_in[11];
  const void* bno  = d_in[12];
  const void* wo   = d_in[13];

  float* ws = (float*)d_ws;
  float* xp    = ws + 16;
  float* z     = xp    + (size_t)BB*LL*DI;
  float* xc    = z     + (size_t)BB*LL*DI;
  float* xh    = xc    + (size_t)BB*LL*DI;
  float* delta = xh    + (size_t)BB*LL*DI;
  float* Bm    = delta + (size_t)BB*KK*LL*DI;
  float* Cm    = Bm    + (size_t)BB*KK*LL*NS;
  float* Acum  = Cm    + (size_t)BB*KK*LL*NS;
  float* Hend  = Acum  + (size_t)GB*NC;
  float* ybuf  = Hend  + (size_t)GB*NC;

  k_inproj_mfma<<<9*32, 256, 0, stream>>>(x, xcr, wi, wc, dsv, xp, z, xc);
  k_inproj_valu<<<6*128, 192, 0, stream>>>(x, xcr, wi, wc, dsv, xp, z, xc);
  k_conv  <<<BB*LL*DI/256, 256, 0, stream>>>(xp, cw, cb, dsv, xh);
  k_xproj <<<BB*KK*(LL/XT), 384, 0, stream>>>(xc, xpw, dtw, dtb, dsv, delta, Bm, Cm);
  k_scanA <<<NCH*NC/256, 256, 0, stream>>>(delta, xh, Bm, alog, dsv, Acum, Hend);
  k_scanB <<<GB/256, 256, 0, stream>>>(Acum, Hend);
  k_scanC <<<NCH*NC/256, 256, 0, stream>>>(delta, xh, Bm, Cm, alog, dsv, Hend, ybuf);
  k_merge <<<BB*LL/8, 256, 0, stream>>>(ybuf, xh, z, dsv, gno, bno, wo, d_out);
}

// Round 8
// 231.580 us; speedup vs baseline: 5.7138x; 1.0330x over previous
//
#include <hip/hip_runtime.h>
#include <hip/hip_bf16.h>
#include <math.h>

#define BB 2
#define HH 32
#define WW 32
#define LL 1024
#define DM 192
#define DI 384
#define NS 16
#define RR 12
#define KK 4
#define CC 44    /* RR + 2*NS */
#define NC 64    /* scan chunks */
#define LC 16    /* chunk length */
#define NCH 3072 /* B*K*DI chains */
#define GB 49152 /* NCH * NS */
#define XT 8     /* xproj positions per block */

// ---- dtype-flex loads (bf: 0=fp32, 1=bf16), derived per-kernel from Ds[0].
// R7 evidence: inputs are fp32 on this harness (valu path ran, mfma path dead);
// the flex mechanism stays as a cheap guard. ----
__device__ __forceinline__ int bfflag(const void* dsv){
  return ((const unsigned*)dsv)[0] != 0x3F800000u;  // fp32 ones vs bf16 pair
}
__device__ __forceinline__ float ldin(const void* p, int i, int bf) {
  if (bf) {
    unsigned v = ((const unsigned short*)p)[i];
    return __uint_as_float(v << 16);
  }
  return ((const float*)p)[i];
}
// 4-wide flex load; i must be a multiple of 4
__device__ __forceinline__ float4 ldin4(const void* p, int i, int bf) {
  if (bf) {
    ushort4 u = ((const ushort4*)p)[i >> 2];
    float4 r;
    r.x = __uint_as_float((unsigned)u.x << 16);
    r.y = __uint_as_float((unsigned)u.y << 16);
    r.z = __uint_as_float((unsigned)u.z << 16);
    r.w = __uint_as_float((unsigned)u.w << 16);
    return r;
  }
  return ((const float4*)p)[i >> 2];
}
__device__ __forceinline__ float sigm(float x){ return 1.f/(1.f + __expf(-x)); }
__device__ __forceinline__ float softplusf(float x){ return (x > 20.f) ? x : log1pf(__expf(x)); }

// scan-index -> physical (row-major h*W+w) index for direction k
__device__ __forceinline__ int permk(int k, int l){
  if (k == 0) return l;
  if (k == 2) return LL-1-l;
  int lr = (k == 3) ? (LL-1-l) : l;
  return (lr & 31)*WW + (lr >> 5);   // (l%H)*W + (l/H)
}

// ---- in-projection as a register-tiled fp32 GEMM ----
// C[2048 x 1152]: rows 0..767 = x @ wi^T, rows 768..1151 = xcr @ wc^T.
// Block: 64 pos x 64 rows, K in three 64-slices via LDS; thread = 4x4 outputs.
__global__ __launch_bounds__(256) void k_inproj(const void* x, const void* xcr,
    const void* wi, const void* wc, const void* dsv,
    float* __restrict__ xp, float* __restrict__ z, float* __restrict__ xcd){
  const int bf = bfflag(dsv);
  __shared__ float As[64][65];     // [k][pos], pad 65 -> conflict-free
  __shared__ float Ws[64][65];     // [k][row]
  const int mb = blockIdx.x & 31;            // 32 M-tiles (2048/64)
  const int nb = blockIdx.x >> 5;            // 18 N-tiles (1152/64)
  const int pos0 = mb*64;
  const int row0g = nb*64;
  const void* src  = (row0g < 768) ? x  : xcr;
  const void* wsrc = (row0g < 768) ? wi : wc;
  const int wrow0 = (row0g < 768) ? row0g : row0g - 768;
  const int t = threadIdx.x;
  const int tx = t & 15, ty = t >> 4;
  float acc[4][4];
  #pragma unroll
  for (int m=0;m<4;m++){
    #pragma unroll
    for (int n=0;n<4;n++) acc[m][n]=0.f;
  }
  for (int k0 = 0; k0 < DM; k0 += 64){
    // stage A-tile and W-tile (4096 elems each; 4 float4 groups per thread each)
    for (int i = t*4; i < 4096; i += 1024){
      const int p = i >> 6, kk = i & 63;     // kk multiple of 4
      const float4 va = ldin4(src,  (pos0 +p)*DM + k0 + kk, bf);
      As[kk+0][p]=va.x; As[kk+1][p]=va.y; As[kk+2][p]=va.z; As[kk+3][p]=va.w;
      const float4 vw = ldin4(wsrc, (wrow0+p)*DM + k0 + kk, bf);
      Ws[kk+0][p]=vw.x; Ws[kk+1][p]=vw.y; Ws[kk+2][p]=vw.z; Ws[kk+3][p]=vw.w;
    }
    __syncthreads();
    #pragma unroll 8
    for (int kk = 0; kk < 64; kk++){
      const float4 a4 = *(const float4*)&As[kk][ty*4];
      const float4 w4 = *(const float4*)&Ws[kk][tx*4];
      acc[0][0]=fmaf(a4.x,w4.x,acc[0][0]); acc[0][1]=fmaf(a4.x,w4.y,acc[0][1]);
      acc[0][2]=fmaf(a4.x,w4.z,acc[0][2]); acc[0][3]=fmaf(a4.x,w4.w,acc[0][3]);
      acc[1][0]=fmaf(a4.y,w4.x,acc[1][0]); acc[1][1]=fmaf(a4.y,w4.y,acc[1][1]);
      acc[1][2]=fmaf(a4.y,w4.z,acc[1][2]); acc[1][3]=fmaf(a4.y,w4.w,acc[1][3]);
      acc[2][0]=fmaf(a4.z,w4.x,acc[2][0]); acc[2][1]=fmaf(a4.z,w4.y,acc[2][1]);
      acc[2][2]=fmaf(a4.z,w4.z,acc[2][2]); acc[2][3]=fmaf(a4.z,w4.w,acc[2][3]);
      acc[3][0]=fmaf(a4.w,w4.x,acc[3][0]); acc[3][1]=fmaf(a4.w,w4.y,acc[3][1]);
      acc[3][2]=fmaf(a4.w,w4.z,acc[3][2]); acc[3][3]=fmaf(a4.w,w4.w,acc[3][3]);
    }
    __syncthreads();
  }
  // store: tile never straddles the xp/z/xc boundaries (all multiples of 64)
  float* dst; int obase;
  if (row0g < 384)      { dst = xp;  obase = row0g; }
  else if (row0g < 768) { dst = z;   obase = row0g-384; }
  else                  { dst = xcd; obase = row0g-768; }
  #pragma unroll
  for (int m=0;m<4;m++){
    const int pos = pos0 + ty*4 + m;
    *(float4*)&dst[(size_t)pos*DI + obase + tx*4] =
        make_float4(acc[m][0], acc[m][1], acc[m][2], acc[m][3]);
  }
}

// depthwise 3x3 conv + bias + SiLU; layout [b, l(=h*W+w), d]
__global__ __launch_bounds__(256) void k_conv(const float* __restrict__ xp,
    const void* cw, const void* cb, const void* dsv, float* __restrict__ xh){
  const int bf = bfflag(dsv);
  const int idx = blockIdx.x*256 + threadIdx.x;    // B*L*DI = 786432 exact
  const int d = idx % DI;
  const int l = (idx / DI) % LL;
  const int b = idx / (DI*LL);
  const int h = l >> 5, w = l & 31;
  float acc = ldin(cb, d, bf);
  #pragma unroll
  for (int kh=0; kh<3; kh++){
    const int hh = h + kh - 1;
    if (hh < 0 || hh >= HH) continue;
    #pragma unroll
    for (int kw=0; kw<3; kw++){
      const int ww2 = w + kw - 1;
      if (ww2 < 0 || ww2 >= WW) continue;
      acc = fmaf(xp[(b*LL + hh*WW + ww2)*DI + d], ldin(cw, d*9 + kh*3 + kw, bf), acc);
    }
  }
  xh[idx] = acc * sigm(acc);
}

// x_proj + dt_proj, 8 positions per 384-thread block. grid = 1024 blocks.
__global__ __launch_bounds__(384) void k_xproj(const float* __restrict__ xc, const void* xpw,
    const void* dtw, const void* dtb, const void* dsv,
    float* __restrict__ delta, float* __restrict__ Bm, float* __restrict__ Cm){
  const int bf = bfflag(dsv);
  const int blk = blockIdx.x;          // 1024
  const int b = blk >> 9;
  const int k = (blk >> 7) & 3;
  const int l0 = (blk & 127) * XT;
  const int t = threadIdx.x;
  __shared__ float xrow[XT][DI+4];     // pad: row stride 388
  __shared__ float dtsS[XT][RR];
  for (int idx = t; idx < XT*96; idx += 384){
    const int j = idx / 96, c = idx % 96;
    const int pl = permk(k, l0 + j);
    *(float4*)&xrow[j][c*4] = *(const float4*)&xc[(b*LL + pl)*DI + c*4];
  }
  __syncthreads();
  if (t < CC*XT){
    const int ch = t >> 3, j = t & 7;
    const int wbase = (k*CC + ch)*DI;
    float a0=0.f, a1=0.f, a2=0.f, a3=0.f;
    for (int c = 0; c < 96; c += 4){
      const float4 w0 = ldin4(xpw, wbase + (c+0)*4, bf);
      const float4 w1 = ldin4(xpw, wbase + (c+1)*4, bf);
      const float4 w2 = ldin4(xpw, wbase + (c+2)*4, bf);
      const float4 w3 = ldin4(xpw, wbase + (c+3)*4, bf);
      const float4 x0 = *(const float4*)&xrow[j][(c+0)*4];
      const float4 x1 = *(const float4*)&xrow[j][(c+1)*4];
      const float4 x2 = *(const float4*)&xrow[j][(c+2)*4];
      const float4 x3 = *(const float4*)&xrow[j][(c+3)*4];
      a0 = fmaf(w0.x,x0.x, fmaf(w0.y,x0.y, fmaf(w0.z,x0.z, fmaf(w0.w,x0.w, a0))));
      a1 = fmaf(w1.x,x1.x, fmaf(w1.y,x1.y, fmaf(w1.z,x1.z, fmaf(w1.w,x1.w, a1))));
      a2 = fmaf(w2.x,x2.x, fmaf(w2.y,x2.y, fmaf(w2.z,x2.z, fmaf(w2.w,x2.w, a2))));
      a3 = fmaf(w3.x,x3.x, fmaf(w3.y,x3.y, fmaf(w3.z,x3.z, fmaf(w3.w,x3.w, a3))));
    }
    const float acc = (a0+a1)+(a2+a3);
    if (ch < RR)           dtsS[j][ch] = acc;
    else if (ch < RR+NS)   Bm[((b*KK+k)*LL + l0+j)*NS + (ch-RR)]    = acc;
    else                   Cm[((b*KK+k)*LL + l0+j)*NS + (ch-RR-NS)] = acc;
  }
  __syncthreads();
  {
    const int d = t;
    float w[RR];
    #pragma unroll
    for (int q = 0; q < 3; q++){
      const float4 w4 = ldin4(dtw, (k*DI+d)*RR + q*4, bf);
      w[q*4+0]=w4.x; w[q*4+1]=w4.y; w[q*4+2]=w4.z; w[q*4+3]=w4.w;
    }
    const float bias = ldin(dtb, k*DI + d, bf);
    #pragma unroll
    for (int j = 0; j < XT; j++){
      float acc = bias;
      #pragma unroll
      for (int r = 0; r < RR; r++) acc = fmaf(w[r], dtsS[j][r], acc);
      xrow[j][d] = softplusf(acc);
    }
  }
  __syncthreads();
  for (int idx = t; idx < XT*96; idx += 384){
    const int j = idx / 96, c = idx % 96;
    *(float4*)&delta[((b*KK+k)*LL + l0+j)*DI + c*4] = *(const float4*)&xrow[j][c*4];
  }
}

// ---- chunked selective scan, 3 passes ----
__global__ __launch_bounds__(256) void k_scanA(const float* __restrict__ delta,
    const float* __restrict__ xh, const float* __restrict__ Bm,
    const void* alogs, const void* dsv,
    float* __restrict__ Acum, float* __restrict__ Hend){
  const int bf = bfflag(dsv);
  const int c = blockIdx.x / 12;              // chunk (uniform per block)
  const int chain = (blockIdx.x % 12)*256 + threadIdx.x;   // (b*K+k)*DI + d
  const int d = chain % DI;
  const int k = (chain / DI) & 3;
  const int b = chain / (DI*KK);
  float An[NS];
  #pragma unroll
  for (int q = 0; q < 4; q++){
    const float4 a4 = ldin4(alogs, (k*DI + d)*NS + q*4, bf);
    An[q*4+0] = -__expf(a4.x); An[q*4+1] = -__expf(a4.y);
    An[q*4+2] = -__expf(a4.z); An[q*4+3] = -__expf(a4.w);
  }
  float h[NS], Ac[NS];
  #pragma unroll
  for (int n = 0; n < NS; n++){ h[n] = 0.f; Ac[n] = 1.f; }
  const int lb = (b*KK+k)*LL;
  const int xbase = b*LL*DI + d;
  const int l0 = c*LC;
  #pragma unroll 4
  for (int l = l0; l < l0+LC; l++){
    const float dl = delta[(lb + l)*DI + d];
    const float u  = xh[xbase + permk(k,l)*DI];
    const float dlu = dl*u;
    const float4 B0 = *(const float4*)&Bm[(lb+l)*NS + 0];
    const float4 B1 = *(const float4*)&Bm[(lb+l)*NS + 4];
    const float4 B2 = *(const float4*)&Bm[(lb+l)*NS + 8];
    const float4 B3 = *(const float4*)&Bm[(lb+l)*NS + 12];
    const float Bv[NS] = {B0.x,B0.y,B0.z,B0.w, B1.x,B1.y,B1.z,B1.w,
                          B2.x,B2.y,B2.z,B2.w, B3.x,B3.y,B3.z,B3.w};
    #pragma unroll
    for (int n = 0; n < NS; n++){
      const float e = __expf(dl*An[n]);
      Ac[n] *= e;
      h[n] = fmaf(e, h[n], dlu*Bv[n]);
    }
  }
  const int obase = (c*NCH + chain)*NS;
  #pragma unroll
  for (int q = 0; q < 4; q++){
    *(float4*)&Acum[obase + q*4] = make_float4(Ac[q*4],Ac[q*4+1],Ac[q*4+2],Ac[q*4+3]);
    *(float4*)&Hend[obase + q*4] = make_float4(h[q*4],h[q*4+1],h[q*4+2],h[q*4+3]);
  }
}

__global__ __launch_bounds__(256) void k_scanB(const float* __restrict__ Acum,
    float* __restrict__ Hend){
  const int g = blockIdx.x*256 + threadIdx.x;   // GB = 49152 threads
  float h = 0.f;
  #pragma unroll 8
  for (int c = 0; c < NC; c++){
    const float a = Acum[c*GB + g];
    const float e = Hend[c*GB + g];
    Hend[c*GB + g] = h;                         // h_in for chunk c
    h = fmaf(a, h, e);
  }
}

__global__ __launch_bounds__(256) void k_scanC(const float* __restrict__ delta,
    const float* __restrict__ xh, const float* __restrict__ Bm,
    const float* __restrict__ Cm, const void* alogs, const void* dsv,
    const float* __restrict__ Hin, float* __restrict__ ybuf){
  const int bf = bfflag(dsv);
  const int c = blockIdx.x / 12;
  const int chain = (blockIdx.x % 12)*256 + threadIdx.x;
  const int d = chain % DI;
  const int k = (chain / DI) & 3;
  const int b = chain / (DI*KK);
  float An[NS];
  #pragma unroll
  for (int q = 0; q < 4; q++){
    const float4 a4 = ldin4(alogs, (k*DI + d)*NS + q*4, bf);
    An[q*4+0] = -__expf(a4.x); An[q*4+1] = -__expf(a4.y);
    An[q*4+2] = -__expf(a4.z); An[q*4+3] = -__expf(a4.w);
  }
  float h[NS];
  const int ibase = (c*NCH + chain)*NS;
  #pragma unroll
  for (int q = 0; q < 4; q++){
    const float4 h4 = *(const float4*)&Hin[ibase + q*4];
    h[q*4+0]=h4.x; h[q*4+1]=h4.y; h[q*4+2]=h4.z; h[q*4+3]=h4.w;
  }
  const int lb = (b*KK+k)*LL;
  const int xbase = b*LL*DI + d;
  const int l0 = c*LC;
  #pragma unroll 4
  for (int l = l0; l < l0+LC; l++){
    const float dl = delta[(lb + l)*DI + d];
    const float u  = xh[xbase + permk(k,l)*DI];
    const float dlu = dl*u;
    const float4 B0 = *(const float4*)&Bm[(lb+l)*NS + 0];
    const float4 B1 = *(const float4*)&Bm[(lb+l)*NS + 4];
    const float4 B2 = *(const float4*)&Bm[(lb+l)*NS + 8];
    const float4 B3 = *(const float4*)&Bm[(lb+l)*NS + 12];
    const float4 C0 = *(const float4*)&Cm[(lb+l)*NS + 0];
    const float4 C1 = *(const float4*)&Cm[(lb+l)*NS + 4];
    const float4 C2 = *(const float4*)&Cm[(lb+l)*NS + 8];
    const float4 C3 = *(const float4*)&Cm[(lb+l)*NS + 12];
    const float Bv[NS] = {B0.x,B0.y,B0.z,B0.w, B1.x,B1.y,B1.z,B1.w,
                          B2.x,B2.y,B2.z,B2.w, B3.x,B3.y,B3.z,B3.w};
    const float Cv[NS] = {C0.x,C0.y,C0.z,C0.w, C1.x,C1.y,C1.z,C1.w,
                          C2.x,C2.y,C2.z,C2.w, C3.x,C3.y,C3.z,C3.w};
    float y = 0.f;
    #pragma unroll
    for (int n = 0; n < NS; n++){
      const float e = __expf(dl*An[n]);
      h[n] = fmaf(e, h[n], dlu*Bv[n]);
      y = fmaf(h[n], Cv[n], y);
    }
    ybuf[(lb + l)*DI + d] = y;
  }
}

// merge + LN (wave-per-position butterfly) + gate + out-proj
__global__ __launch_bounds__(256) void k_merge(const float* __restrict__ scanY,
    const float* __restrict__ xh, const float* __restrict__ z,
    const void* dsP, const void* gP, const void* bP, const void* woP,
    void* out){
  const int bf = bfflag(dsP);
  const int blk = blockIdx.x;          // 256
  const int t = threadIdx.x;
  const int wv = t >> 6, lane = t & 63;
  __shared__ float ygs[8][DI];
  #pragma unroll
  for (int rep = 0; rep < 2; rep++){
    const int j = wv*2 + rep;
    const int pos = blk*8 + j;
    const int b = pos >> 10, l = pos & 1023;
    const int lt = (l & 31)*32 + (l >> 5);
    float yv[6];
    float s = 0.f, s2 = 0.f;
    #pragma unroll
    for (int i = 0; i < 6; i++){
      const int d = i*64 + lane;
      float y = scanY[((b*KK+0)*LL + l        )*DI + d]
              + scanY[((b*KK+2)*LL + (LL-1-l ))*DI + d]
              + scanY[((b*KK+1)*LL + lt       )*DI + d]
              + scanY[((b*KK+3)*LL + (LL-1-lt))*DI + d];
      const float dsum = ldin(dsP, d, bf) + ldin(dsP, DI+d, bf)
                       + ldin(dsP, 2*DI+d, bf) + ldin(dsP, 3*DI+d, bf);
      y = fmaf(xh[(b*LL+l)*DI + d], dsum, y);
      yv[i] = y;
      s += y; s2 = fmaf(y, y, s2);
    }
    #pragma unroll
    for (int m = 1; m < 64; m <<= 1){
      s  += __shfl_xor(s,  m);
      s2 += __shfl_xor(s2, m);
    }
    const float mu = s * (1.f/DI);
    const float var = fmaxf(s2 * (1.f/DI) - mu*mu, 0.f);
    const float rs = rsqrtf(var + 1e-5f);
    #pragma unroll
    for (int i = 0; i < 6; i++){
      const int d = i*64 + lane;
      const float yn = (yv[i]-mu)*rs*ldin(gP, d, bf) + ldin(bP, d, bf);
      const float zg = z[(b*LL+l)*DI + d];
      ygs[j][d] = yn * zg * sigm(zg);
    }
  }
  __syncthreads();
  if (t < DM){
    const int o = t;
    float acc[8];
    #pragma unroll
    for (int j=0;j<8;j++) acc[j] = 0.f;
    for (int c = 0; c < 96; c++){
      const float4 w4 = ldin4(woP, o*DI + c*4, bf);
      #pragma unroll
      for (int j=0;j<8;j++){
        const float4 y4 = *(const float4*)&ygs[j][c*4];
        acc[j] = fmaf(w4.x, y4.x, acc[j]);
        acc[j] = fmaf(w4.y, y4.y, acc[j]);
        acc[j] = fmaf(w4.z, y4.z, acc[j]);
        acc[j] = fmaf(w4.w, y4.w, acc[j]);
      }
    }
    #pragma unroll
    for (int j=0;j<8;j++){
      const int pos = blk*8 + j;
      if (bf) ((__hip_bfloat16*)out)[pos*DM + o] = __float2bfloat16(acc[j]);
      else    ((float*)out)[pos*DM + o] = acc[j];
    }
  }
}

extern "C" void kernel_launch(void* const* d_in, const int* in_sizes, int n_in,
                              void* d_out, int out_size, void* d_ws, size_t ws_size,
                              hipStream_t stream){
  const void* x    = d_in[0];
  const void* xcr  = d_in[1];
  const void* wi   = d_in[2];
  const void* wc   = d_in[3];
  const void* cw   = d_in[4];
  const void* cb   = d_in[5];
  const void* xpw  = d_in[6];
  const void* dtw  = d_in[7];
  const void* dtb  = d_in[8];
  const void* alog = d_in[9];
  const void* dsv  = d_in[10];
  const void* gno  = d_in[11];
  const void* bno  = d_in[12];
  const void* wo   = d_in[13];

  float* ws = (float*)d_ws;
  float* xp    = ws + 16;
  float* z     = xp    + (size_t)BB*LL*DI;
  float* xc    = z     + (size_t)BB*LL*DI;
  float* xh    = xc    + (size_t)BB*LL*DI;
  float* delta = xh    + (size_t)BB*LL*DI;
  float* Bm    = delta + (size_t)BB*KK*LL*DI;
  float* Cm    = Bm    + (size_t)BB*KK*LL*NS;
  float* Acum  = Cm    + (size_t)BB*KK*LL*NS;
  float* Hend  = Acum  + (size_t)GB*NC;
  float* ybuf  = Hend  + (size_t)GB*NC;

  k_inproj<<<18*32, 256, 0, stream>>>(x, xcr, wi, wc, dsv, xp, z, xc);
  k_conv  <<<BB*LL*DI/256, 256, 0, stream>>>(xp, cw, cb, dsv, xh);
  k_xproj <<<BB*KK*(LL/XT), 384, 0, stream>>>(xc, xpw, dtw, dtb, dsv, delta, Bm, Cm);
  k_scanA <<<NCH*NC/256, 256, 0, stream>>>(delta, xh, Bm, alog, dsv, Acum, Hend);
  k_scanB <<<GB/256, 256, 0, stream>>>(Acum, Hend);
  k_scanC <<<NCH*NC/256, 256, 0, stream>>>(delta, xh, Bm, Cm, alog, dsv, Hend, ybuf);
  k_merge <<<BB*LL/8, 256, 0, stream>>>(ybuf, xh, z, dsv, gno, bno, wo, d_out);
}

// Round 9
// 223.861 us; speedup vs baseline: 5.9108x; 1.0345x over previous
//
#include <hip/hip_runtime.h>
#include <hip/hip_bf16.h>
#include <math.h>

#define BB 2
#define HH 32
#define WW 32
#define LL 1024
#define DM 192
#define DI 384
#define NS 16
#define RR 12
#define KK 4
#define CC 44    /* RR + 2*NS */
#define NC 64    /* scan chunks */
#define LC 16    /* chunk length == fused xproj tile */
#define NCH 3072 /* B*K*DI chains */
#define GB 49152 /* NCH * NS */

// ---- dtype-flex loads (bf: 0=fp32, 1=bf16), derived per-kernel from Ds[0].
// R7 evidence: inputs are fp32 on this harness; flex stays as a cheap guard. ----
__device__ __forceinline__ int bfflag(const void* dsv){
  return ((const unsigned*)dsv)[0] != 0x3F800000u;
}
__device__ __forceinline__ float ldin(const void* p, int i, int bf) {
  if (bf) {
    unsigned v = ((const unsigned short*)p)[i];
    return __uint_as_float(v << 16);
  }
  return ((const float*)p)[i];
}
__device__ __forceinline__ float4 ldin4(const void* p, int i, int bf) {
  if (bf) {
    ushort4 u = ((const ushort4*)p)[i >> 2];
    float4 r;
    r.x = __uint_as_float((unsigned)u.x << 16);
    r.y = __uint_as_float((unsigned)u.y << 16);
    r.z = __uint_as_float((unsigned)u.z << 16);
    r.w = __uint_as_float((unsigned)u.w << 16);
    return r;
  }
  return ((const float4*)p)[i >> 2];
}
__device__ __forceinline__ float sigm(float x){ return 1.f/(1.f + __expf(-x)); }
__device__ __forceinline__ float softplusf(float x){ return (x > 20.f) ? x : log1pf(__expf(x)); }

__device__ __forceinline__ int permk(int k, int l){
  if (k == 0) return l;
  if (k == 2) return LL-1-l;
  int lr = (k == 3) ? (LL-1-l) : l;
  return (lr & 31)*WW + (lr >> 5);
}

// ---- in-projection as a register-tiled fp32 GEMM (R8, kept) ----
__global__ __launch_bounds__(256) void k_inproj(const void* x, const void* xcr,
    const void* wi, const void* wc, const void* dsv,
    float* __restrict__ xp, float* __restrict__ z, float* __restrict__ xcd){
  const int bf = bfflag(dsv);
  __shared__ float As[64][65];
  __shared__ float Ws[64][65];
  const int mb = blockIdx.x & 31;
  const int nb = blockIdx.x >> 5;
  const int pos0 = mb*64;
  const int row0g = nb*64;
  const void* src  = (row0g < 768) ? x  : xcr;
  const void* wsrc = (row0g < 768) ? wi : wc;
  const int wrow0 = (row0g < 768) ? row0g : row0g - 768;
  const int t = threadIdx.x;
  const int tx = t & 15, ty = t >> 4;
  float acc[4][4];
  #pragma unroll
  for (int m=0;m<4;m++){
    #pragma unroll
    for (int n=0;n<4;n++) acc[m][n]=0.f;
  }
  for (int k0 = 0; k0 < DM; k0 += 64){
    for (int i = t*4; i < 4096; i += 1024){
      const int p = i >> 6, kk = i & 63;
      const float4 va = ldin4(src,  (pos0 +p)*DM + k0 + kk, bf);
      As[kk+0][p]=va.x; As[kk+1][p]=va.y; As[kk+2][p]=va.z; As[kk+3][p]=va.w;
      const float4 vw = ldin4(wsrc, (wrow0+p)*DM + k0 + kk, bf);
      Ws[kk+0][p]=vw.x; Ws[kk+1][p]=vw.y; Ws[kk+2][p]=vw.z; Ws[kk+3][p]=vw.w;
    }
    __syncthreads();
    #pragma unroll 8
    for (int kk = 0; kk < 64; kk++){
      const float4 a4 = *(const float4*)&As[kk][ty*4];
      const float4 w4 = *(const float4*)&Ws[kk][tx*4];
      acc[0][0]=fmaf(a4.x,w4.x,acc[0][0]); acc[0][1]=fmaf(a4.x,w4.y,acc[0][1]);
      acc[0][2]=fmaf(a4.x,w4.z,acc[0][2]); acc[0][3]=fmaf(a4.x,w4.w,acc[0][3]);
      acc[1][0]=fmaf(a4.y,w4.x,acc[1][0]); acc[1][1]=fmaf(a4.y,w4.y,acc[1][1]);
      acc[1][2]=fmaf(a4.y,w4.z,acc[1][2]); acc[1][3]=fmaf(a4.y,w4.w,acc[1][3]);
      acc[2][0]=fmaf(a4.z,w4.x,acc[2][0]); acc[2][1]=fmaf(a4.z,w4.y,acc[2][1]);
      acc[2][2]=fmaf(a4.z,w4.z,acc[2][2]); acc[2][3]=fmaf(a4.z,w4.w,acc[2][3]);
      acc[3][0]=fmaf(a4.w,w4.x,acc[3][0]); acc[3][1]=fmaf(a4.w,w4.y,acc[3][1]);
      acc[3][2]=fmaf(a4.w,w4.z,acc[3][2]); acc[3][3]=fmaf(a4.w,w4.w,acc[3][3]);
    }
    __syncthreads();
  }
  float* dst; int obase;
  if (row0g < 384)      { dst = xp;  obase = row0g; }
  else if (row0g < 768) { dst = z;   obase = row0g-384; }
  else                  { dst = xcd; obase = row0g-768; }
  #pragma unroll
  for (int m=0;m<4;m++){
    const int pos = pos0 + ty*4 + m;
    *(float4*)&dst[(size_t)pos*DI + obase + tx*4] =
        make_float4(acc[m][0], acc[m][1], acc[m][2], acc[m][3]);
  }
}

// depthwise 3x3 conv + bias + SiLU; layout [b, l(=h*W+w), d]
__global__ __launch_bounds__(256) void k_conv(const float* __restrict__ xp,
    const void* cw, const void* cb, const void* dsv, float* __restrict__ xh){
  const int bf = bfflag(dsv);
  const int idx = blockIdx.x*256 + threadIdx.x;
  const int d = idx % DI;
  const int l = (idx / DI) % LL;
  const int b = idx / (DI*LL);
  const int h = l >> 5, w = l & 31;
  float acc = ldin(cb, d, bf);
  #pragma unroll
  for (int kh=0; kh<3; kh++){
    const int hh = h + kh - 1;
    if (hh < 0 || hh >= HH) continue;
    #pragma unroll
    for (int kw=0; kw<3; kw++){
      const int ww2 = w + kw - 1;
      if (ww2 < 0 || ww2 >= WW) continue;
      acc = fmaf(xp[(b*LL + hh*WW + ww2)*DI + d], ldin(cw, d*9 + kh*3 + kw, bf), acc);
    }
  }
  xh[idx] = acc * sigm(acc);
}

// ---- fused x_proj + dt_proj + scan pass A ----
// block = (b, k, chunk of LC=16 scan indices), 384 threads.
// xproj phases fill xrow (delta in LDS) + Bs; scan-A phase consumes them from
// LDS (no global round-trip), writing Acum/Hend. delta/Bm/Cm still stored for
// pass C.
__global__ __launch_bounds__(384) void k_xscanA(const float* __restrict__ xc,
    const float* __restrict__ xh, const void* xpw, const void* dtw,
    const void* dtb, const void* alogs, const void* dsv,
    float* __restrict__ delta, float* __restrict__ Bm, float* __restrict__ Cm,
    float* __restrict__ Acum, float* __restrict__ Hend){
  const int bf = bfflag(dsv);
  const int blk = blockIdx.x;          // B*K*NC = 512
  const int b = blk >> 8;
  const int k = (blk >> 6) & 3;
  const int c = blk & 63;
  const int l0 = c * LC;
  const int t = threadIdx.x;
  __shared__ float xrow[LC][DI+4];     // activations, then delta (post dt_proj)
  __shared__ float dtsS[LC][RR];
  __shared__ float Bs[LC][NS];
  // stage 16 permuted activation rows (1536 float4 / 384 = 4 rounds)
  for (int idx = t; idx < LC*96; idx += 384){
    const int j = idx / 96, cc = idx % 96;
    const int pl = permk(k, l0 + j);
    *(float4*)&xrow[j][cc*4] = *(const float4*)&xc[(b*LL + pl)*DI + cc*4];
  }
  __syncthreads();
  // x_dbl: 44 channels x 16 positions = 704 dots
  for (int idx = t; idx < CC*LC; idx += 384){
    const int ch = idx >> 4, j = idx & 15;
    const int wbase = (k*CC + ch)*DI;
    float a0=0.f, a1=0.f, a2=0.f, a3=0.f;
    for (int cc = 0; cc < 96; cc += 4){
      const float4 w0 = ldin4(xpw, wbase + (cc+0)*4, bf);
      const float4 w1 = ldin4(xpw, wbase + (cc+1)*4, bf);
      const float4 w2 = ldin4(xpw, wbase + (cc+2)*4, bf);
      const float4 w3 = ldin4(xpw, wbase + (cc+3)*4, bf);
      const float4 x0 = *(const float4*)&xrow[j][(cc+0)*4];
      const float4 x1 = *(const float4*)&xrow[j][(cc+1)*4];
      const float4 x2 = *(const float4*)&xrow[j][(cc+2)*4];
      const float4 x3 = *(const float4*)&xrow[j][(cc+3)*4];
      a0 = fmaf(w0.x,x0.x, fmaf(w0.y,x0.y, fmaf(w0.z,x0.z, fmaf(w0.w,x0.w, a0))));
      a1 = fmaf(w1.x,x1.x, fmaf(w1.y,x1.y, fmaf(w1.z,x1.z, fmaf(w1.w,x1.w, a1))));
      a2 = fmaf(w2.x,x2.x, fmaf(w2.y,x2.y, fmaf(w2.z,x2.z, fmaf(w2.w,x2.w, a2))));
      a3 = fmaf(w3.x,x3.x, fmaf(w3.y,x3.y, fmaf(w3.z,x3.z, fmaf(w3.w,x3.w, a3))));
    }
    const float acc = (a0+a1)+(a2+a3);
    if (ch < RR)          dtsS[j][ch] = acc;
    else if (ch < RR+NS){ Bs[j][ch-RR] = acc;
                          Bm[((b*KK+k)*LL + l0+j)*NS + (ch-RR)]    = acc; }
    else                  Cm[((b*KK+k)*LL + l0+j)*NS + (ch-RR-NS)] = acc;
  }
  __syncthreads();
  // dt_proj + softplus: d = t (384 == DI); xrow consumed pre-barrier -> overwrite
  {
    const int d = t;
    float w[RR];
    #pragma unroll
    for (int q = 0; q < 3; q++){
      const float4 w4 = ldin4(dtw, (k*DI+d)*RR + q*4, bf);
      w[q*4+0]=w4.x; w[q*4+1]=w4.y; w[q*4+2]=w4.z; w[q*4+3]=w4.w;
    }
    const float bias = ldin(dtb, k*DI + d, bf);
    #pragma unroll
    for (int j = 0; j < LC; j++){
      float acc = bias;
      #pragma unroll
      for (int r = 0; r < RR; r++) acc = fmaf(w[r], dtsS[j][r], acc);
      xrow[j][d] = softplusf(acc);
    }
  }
  __syncthreads();
  // delta store for pass C (fire early; scan phase computes while in flight)
  for (int idx = t; idx < LC*96; idx += 384){
    const int j = idx / 96, cc = idx % 96;
    *(float4*)&delta[((b*KK+k)*LL + l0+j)*DI + cc*4] = *(const float4*)&xrow[j][cc*4];
  }
  // scan pass A: chain d = t, all 16 states in registers; delta/B from LDS
  {
    const int d = t;
    float An[NS];
    #pragma unroll
    for (int q = 0; q < 4; q++){
      const float4 a4 = ldin4(alogs, (k*DI + d)*NS + q*4, bf);
      An[q*4+0] = -__expf(a4.x); An[q*4+1] = -__expf(a4.y);
      An[q*4+2] = -__expf(a4.z); An[q*4+3] = -__expf(a4.w);
    }
    float h[NS], Ac[NS];
    #pragma unroll
    for (int n = 0; n < NS; n++){ h[n] = 0.f; Ac[n] = 1.f; }
    const int xbase = b*LL*DI + d;
    #pragma unroll 4
    for (int j = 0; j < LC; j++){
      const int l = l0 + j;
      const float dl = xrow[j][d];
      const float u  = xh[xbase + permk(k,l)*DI];
      const float dlu = dl*u;
      #pragma unroll
      for (int n = 0; n < NS; n++){
        const float e = __expf(dl*An[n]);
        Ac[n] *= e;
        h[n] = fmaf(e, h[n], dlu*Bs[j][n]);
      }
    }
    const int chain = (b*KK + k)*DI + d;
    const int obase = (c*NCH + chain)*NS;
    #pragma unroll
    for (int q = 0; q < 4; q++){
      *(float4*)&Acum[obase + q*4] = make_float4(Ac[q*4],Ac[q*4+1],Ac[q*4+2],Ac[q*4+3]);
      *(float4*)&Hend[obase + q*4] = make_float4(h[q*4],h[q*4+1],h[q*4+2],h[q*4+3]);
    }
  }
}

__global__ __launch_bounds__(256) void k_scanB(const float* __restrict__ Acum,
    float* __restrict__ Hend){
  const int g = blockIdx.x*256 + threadIdx.x;   // GB threads
  float h = 0.f;
  #pragma unroll 8
  for (int c = 0; c < NC; c++){
    const float a = Acum[c*GB + g];
    const float e = Hend[c*GB + g];
    Hend[c*GB + g] = h;
    h = fmaf(a, h, e);
  }
}

__global__ __launch_bounds__(256) void k_scanC(const float* __restrict__ delta,
    const float* __restrict__ xh, const float* __restrict__ Bm,
    const float* __restrict__ Cm, const void* alogs, const void* dsv,
    const float* __restrict__ Hin, float* __restrict__ ybuf){
  const int bf = bfflag(dsv);
  const int c = blockIdx.x / 12;
  const int chain = (blockIdx.x % 12)*256 + threadIdx.x;
  const int d = chain % DI;
  const int k = (chain / DI) & 3;
  const int b = chain / (DI*KK);
  float An[NS];
  #pragma unroll
  for (int q = 0; q < 4; q++){
    const float4 a4 = ldin4(alogs, (k*DI + d)*NS + q*4, bf);
    An[q*4+0] = -__expf(a4.x); An[q*4+1] = -__expf(a4.y);
    An[q*4+2] = -__expf(a4.z); An[q*4+3] = -__expf(a4.w);
  }
  float h[NS];
  const int ibase = (c*NCH + chain)*NS;
  #pragma unroll
  for (int q = 0; q < 4; q++){
    const float4 h4 = *(const float4*)&Hin[ibase + q*4];
    h[q*4+0]=h4.x; h[q*4+1]=h4.y; h[q*4+2]=h4.z; h[q*4+3]=h4.w;
  }
  const int lb = (b*KK+k)*LL;
  const int xbase = b*LL*DI + d;
  const int l0 = c*LC;
  #pragma unroll 4
  for (int l = l0; l < l0+LC; l++){
    const float dl = delta[(lb + l)*DI + d];
    const float u  = xh[xbase + permk(k,l)*DI];
    const float dlu = dl*u;
    const float4 B0 = *(const float4*)&Bm[(lb+l)*NS + 0];
    const float4 B1 = *(const float4*)&Bm[(lb+l)*NS + 4];
    const float4 B2 = *(const float4*)&Bm[(lb+l)*NS + 8];
    const float4 B3 = *(const float4*)&Bm[(lb+l)*NS + 12];
    const float4 C0 = *(const float4*)&Cm[(lb+l)*NS + 0];
    const float4 C1 = *(const float4*)&Cm[(lb+l)*NS + 4];
    const float4 C2 = *(const float4*)&Cm[(lb+l)*NS + 8];
    const float4 C3 = *(const float4*)&Cm[(lb+l)*NS + 12];
    const float Bv[NS] = {B0.x,B0.y,B0.z,B0.w, B1.x,B1.y,B1.z,B1.w,
                          B2.x,B2.y,B2.z,B2.w, B3.x,B3.y,B3.z,B3.w};
    const float Cv[NS] = {C0.x,C0.y,C0.z,C0.w, C1.x,C1.y,C1.z,C1.w,
                          C2.x,C2.y,C2.z,C2.w, C3.x,C3.y,C3.z,C3.w};
    float y = 0.f;
    #pragma unroll
    for (int n = 0; n < NS; n++){
      const float e = __expf(dl*An[n]);
      h[n] = fmaf(e, h[n], dlu*Bv[n]);
      y = fmaf(h[n], Cv[n], y);
    }
    ybuf[(lb + l)*DI + d] = y;
  }
}

// merge + LN (wave-per-position butterfly) + gate + out-proj
// 4 positions per block, 512 blocks (2 blocks/CU vs R8's 1).
__global__ __launch_bounds__(256) void k_merge(const float* __restrict__ scanY,
    const float* __restrict__ xh, const float* __restrict__ z,
    const void* dsP, const void* gP, const void* bP, const void* woP,
    void* out){
  const int bf = bfflag(dsP);
  const int blk = blockIdx.x;          // 512
  const int t = threadIdx.x;
  const int wv = t >> 6, lane = t & 63;
  __shared__ float ygs[4][DI];
  {
    const int j = wv;
    const int pos = blk*4 + j;
    const int b = pos >> 10, l = pos & 1023;
    const int lt = (l & 31)*32 + (l >> 5);
    float yv[6];
    float s = 0.f, s2 = 0.f;
    #pragma unroll
    for (int i = 0; i < 6; i++){
      const int d = i*64 + lane;
      float y = scanY[((b*KK+0)*LL + l        )*DI + d]
              + scanY[((b*KK+2)*LL + (LL-1-l ))*DI + d]
              + scanY[((b*KK+1)*LL + lt       )*DI + d]
              + scanY[((b*KK+3)*LL + (LL-1-lt))*DI + d];
      const float dsum = ldin(dsP, d, bf) + ldin(dsP, DI+d, bf)
                       + ldin(dsP, 2*DI+d, bf) + ldin(dsP, 3*DI+d, bf);
      y = fmaf(xh[(b*LL+l)*DI + d], dsum, y);
      yv[i] = y;
      s += y; s2 = fmaf(y, y, s2);
    }
    #pragma unroll
    for (int m = 1; m < 64; m <<= 1){
      s  += __shfl_xor(s,  m);
      s2 += __shfl_xor(s2, m);
    }
    const float mu = s * (1.f/DI);
    const float var = fmaxf(s2 * (1.f/DI) - mu*mu, 0.f);
    const float rs = rsqrtf(var + 1e-5f);
    #pragma unroll
    for (int i = 0; i < 6; i++){
      const int d = i*64 + lane;
      const float yn = (yv[i]-mu)*rs*ldin(gP, d, bf) + ldin(bP, d, bf);
      const float zg = z[(b*LL+l)*DI + d];
      ygs[j][d] = yn * zg * sigm(zg);
    }
  }
  __syncthreads();
  if (t < DM){
    const int o = t;
    float acc[4];
    #pragma unroll
    for (int j=0;j<4;j++) acc[j] = 0.f;
    for (int cc = 0; cc < 96; cc++){
      const float4 w4 = ldin4(woP, o*DI + cc*4, bf);
      #pragma unroll
      for (int j=0;j<4;j++){
        const float4 y4 = *(const float4*)&ygs[j][cc*4];
        acc[j] = fmaf(w4.x, y4.x, acc[j]);
        acc[j] = fmaf(w4.y, y4.y, acc[j]);
        acc[j] = fmaf(w4.z, y4.z, acc[j]);
        acc[j] = fmaf(w4.w, y4.w, acc[j]);
      }
    }
    #pragma unroll
    for (int j=0;j<4;j++){
      const int pos = blk*4 + j;
      if (bf) ((__hip_bfloat16*)out)[pos*DM + o] = __float2bfloat16(acc[j]);
      else    ((float*)out)[pos*DM + o] = acc[j];
    }
  }
}

extern "C" void kernel_launch(void* const* d_in, const int* in_sizes, int n_in,
                              void* d_out, int out_size, void* d_ws, size_t ws_size,
                              hipStream_t stream){
  const void* x    = d_in[0];
  const void* xcr  = d_in[1];
  const void* wi   = d_in[2];
  const void* wc   = d_in[3];
  const void* cw   = d_in[4];
  const void* cb   = d_in[5];
  const void* xpw  = d_in[6];
  const void* dtw  = d_in[7];
  const void* dtb  = d_in[8];
  const void* alog = d_in[9];
  const void* dsv  = d_in[10];
  const void* gno  = d_in[11];
  const void* bno  = d_in[12];
  const void* wo   = d_in[13];

  float* ws = (float*)d_ws;
  float* xp    = ws + 16;
  float* z     = xp    + (size_t)BB*LL*DI;
  float* xc    = z     + (size_t)BB*LL*DI;
  float* xh    = xc    + (size_t)BB*LL*DI;
  float* delta = xh    + (size_t)BB*LL*DI;
  float* Bm    = delta + (size_t)BB*KK*LL*DI;
  float* Cm    = Bm    + (size_t)BB*KK*LL*NS;
  float* Acum  = Cm    + (size_t)BB*KK*LL*NS;
  float* Hend  = Acum  + (size_t)GB*NC;
  float* ybuf  = Hend  + (size_t)GB*NC;

  k_inproj<<<18*32, 256, 0, stream>>>(x, xcr, wi, wc, dsv, xp, z, xc);
  k_conv  <<<BB*LL*DI/256, 256, 0, stream>>>(xp, cw, cb, dsv, xh);
  k_xscanA<<<BB*KK*NC, 384, 0, stream>>>(xc, xh, xpw, dtw, dtb, alog, dsv,
                                         delta, Bm, Cm, Acum, Hend);
  k_scanB <<<GB/256, 256, 0, stream>>>(Acum, Hend);
  k_scanC <<<NCH*NC/256, 256, 0, stream>>>(delta, xh, Bm, Cm, alog, dsv, Hend, ybuf);
  k_merge <<<BB*LL/4, 256, 0, stream>>>(ybuf, xh, z, dsv, gno, bno, wo, d_out);
}